// Round 10
// baseline (82.789 us; speedup 1.0000x reference)
//
#include <hip/hip_runtime.h>
#include <hip/hip_bf16.h>

#define BB 4096
#define NNB 20
#define GG 4
#define DIN 128
#define EE 64
#define HH 8

typedef short bf16x8 __attribute__((ext_vector_type(8)));
typedef float f32x4 __attribute__((ext_vector_type(4)));

__device__ __forceinline__ float lrelu_f(float x) { return x > 0.f ? x : 0.2f * x; }
__device__ __forceinline__ unsigned short f2bf(float f) {
  unsigned u = __float_as_uint(f);
  return (unsigned short)((u + 0x7fffu + ((u >> 16) & 1u)) >> 16);
}
__device__ __forceinline__ float bf2f(unsigned short s) {
  return __uint_as_float(((unsigned)s) << 16);
}

// ---------------- K0: prep (unchanged) ----------------
__global__ __launch_bounds__(256) void prep_kernel(
    const float* __restrict__ W_heads, const float* __restrict__ a_self,
    const float* __restrict__ a_neigh, const float* __restrict__ W_out,
    unsigned short* __restrict__ P1Whi, unsigned short* __restrict__ P1Wlo,
    unsigned short* __restrict__ WBhi, unsigned short* __restrict__ WBlo,
    unsigned short* __restrict__ WOhi, unsigned short* __restrict__ WOlo) {
  int id = blockIdx.x * 256 + threadIdx.x;
  if (id < 2048) {
    int j = id & 7, lane = (id >> 3) & 63, kb = id >> 9;
    int col = lane & 15, k = kb * 32 + (lane >> 4) * 8 + j;
    int h = col & 7;
    const float* a = (col < 8) ? a_neigh : a_self;
    const float* Wrow = W_heads + (h * DIN + k) * EE;
    float acc = 0.f;
    for (int e = 0; e < EE; ++e) acc = fmaf(Wrow[e], a[h * EE + e], acc);
    unsigned short hi = f2bf(acc);
    P1Whi[id] = hi;
    P1Wlo[id] = f2bf(acc - bf2f(hi));
  } else if (id < 2048 + 65536) {
    int rel = id - 2048;   // (((h*4+nt)*4+kb)*64 + l)*8 + j
    int j = rel & 7, l = (rel >> 3) & 63, kb = (rel >> 9) & 3, nt = (rel >> 11) & 3, h = rel >> 13;
    int d = kb * 32 + (l >> 4) * 8 + j;
    int e = nt * 16 + (l & 15);
    float w = W_heads[(h * DIN + d) * EE + e];
    unsigned short hi = f2bf(w);
    WBhi[rel] = hi;
    WBlo[rel] = f2bf(w - bf2f(hi));
  } else if (id < 2048 + 65536 + 32768) {
    int rel = id - 2048 - 65536;  // ((nt*16+kb)*64 + l)*8 + j
    int j = rel & 7, l = (rel >> 3) & 63, kb = (rel >> 9) & 15, nt = rel >> 13;
    int k = kb * 32 + (l >> 4) * 8 + j;
    int n = nt * 16 + (l & 15);
    float w = W_out[k * EE + n];
    unsigned short hi = f2bf(w);
    WOhi[rel] = hi;
    WOlo[rel] = f2bf(w - bf2f(hi));
  }
}

// ---------------- Fused kernel: 512 threads (8 waves), 4 b's = 16 bg rows ----------------
// Identical to R9 except __launch_bounds__(512, 6): caps VGPR <= ~85 so
// 3 blocks/CU (24 waves) fit; LDS 53,760 B * 3 = 161,280 <= 163,840.
__global__ __launch_bounds__(512, 6) void fused_kernel(
    const float* __restrict__ self_vecs, const float* __restrict__ neigh_vecs,
    const unsigned short* __restrict__ P1Whi, const unsigned short* __restrict__ P1Wlo,
    const unsigned short* __restrict__ WBhi, const unsigned short* __restrict__ WBlo,
    const unsigned short* __restrict__ WOhi, const unsigned short* __restrict__ WOlo,
    float* __restrict__ out) {
  __shared__ char smem[53760];
  char* aggb = smem;
  float* fw   = (float*)(smem + 32768);   // f words
  float* attw = (float*)(smem + 43520);   // att words
  char* hb = smem + 32768;                // h_s bytes (reuse)

  const int t = threadIdx.x;
  const int w = t >> 6, lane = t & 63;
  const int m = lane & 15, kg = lane >> 4;
  const int bid = blockIdx.x;

  // P1 weight frags (B operand)
  bf16x8 wfh[4], wfl[4];
#pragma unroll
  for (int kb = 0; kb < 4; ++kb) {
    wfh[kb] = *(const bf16x8*)(P1Whi + (kb * 64 + lane) * 8);
    wfl[kb] = *(const bf16x8*)(P1Wlo + (kb * 64 + lane) * 8);
  }

  // ======== P1: f = X_cat x W_cat via MFMA straight from global ========
  const int bl_m = m >> 2, g_m = m & 3;
  for (int tile = w; tile < 21; tile += 8) {
    const float* rowp;
    if (tile < 20)
      rowp = neigh_vecs + (((size_t)(bid * 4 + bl_m) * NNB + tile) * GG + g_m) * DIN;
    else
      rowp = self_vecs + ((size_t)bid * 16 + m) * DIN;
    f32x4 c = {0.f, 0.f, 0.f, 0.f};
#pragma unroll
    for (int kb = 0; kb < 4; ++kb) {
      float4 xa = *(const float4*)(rowp + kb * 32 + kg * 8);
      float4 xb = *(const float4*)(rowp + kb * 32 + kg * 8 + 4);
      float xv[8] = {xa.x, xa.y, xa.z, xa.w, xb.x, xb.y, xb.z, xb.w};
      bf16x8 xh, xl;
#pragma unroll
      for (int j = 0; j < 8; ++j) {
        unsigned short hi = f2bf(xv[j]);
        xh[j] = (short)hi;
        xl[j] = (short)f2bf(xv[j] - bf2f(hi));
      }
      c = __builtin_amdgcn_mfma_f32_16x16x32_bf16(xh, wfh[kb], c, 0, 0, 0);
      c = __builtin_amdgcn_mfma_f32_16x16x32_bf16(xh, wfl[kb], c, 0, 0, 0);
      c = __builtin_amdgcn_mfma_f32_16x16x32_bf16(xl, wfh[kb], c, 0, 0, 0);
    }
    // D: col = m = head-col, row = kg*4+reg = bg
    if (tile < 20) {
      if (m < 8) {
#pragma unroll
        for (int reg = 0; reg < 4; ++reg) {
          int row = kg * 4 + reg;
          fw[tile * 128 + ((row * 8 + m) ^ (kg << 3))] = c[reg];
        }
      }
    } else {
      if (m >= 8) {
#pragma unroll
        for (int reg = 0; reg < 4; ++reg) {
          int row = kg * 4 + reg;
          fw[20 * 128 + ((row * 8 + (m - 8)) ^ (kg << 3))] = c[reg];
        }
      }
    }
  }
  __syncthreads();

  // ======== P2: leaky-relu + softmax over g ========
#pragma unroll
  for (int it = 0; it < 2; ++it) {
    int task = t + it * 512;           // task = (n*8+h)*4 + bl
    if (task < 640) {
      int bl = task & 3, h = (task >> 2) & 7, n = task >> 5;
      float l[4], mx = -1e30f;
#pragma unroll
      for (int gg = 0; gg < 4; ++gg) {
        int bg = bl * 4 + gg;
        float fn = fw[n * 128 + ((bg * 8 + h) ^ (bl << 3))];
        float fs = fw[20 * 128 + ((bg * 8 + h) ^ (bl << 3))];
        float v = lrelu_f(fs + fn);
        l[gg] = v;
        mx = fmaxf(mx, v);
      }
      float s = 0.f;
#pragma unroll
      for (int gg = 0; gg < 4; ++gg) { l[gg] = __expf(l[gg] - mx); s += l[gg]; }
      float inv = 1.f / s;
#pragma unroll
      for (int gg = 0; gg < 4; ++gg)
        attw[n * 128 + (((bl * 4 + gg) * 8 + h) ^ (bl << 3))] = l[gg] * inv;
    }
  }
  __syncthreads();

  // ======== P3: agg[bg][h][d] = sum_n att*x ; wave w -> bg {2w, 2w+1} ========
#pragma unroll
  for (int i = 0; i < 2; ++i) {
    const int bg = 2 * w + i;
    const int bl = bg >> 2, g = bg & 3;
    const float* nbw = neigh_vecs + ((size_t)(bid * 4 + bl) * NNB * GG + g) * DIN;
    float acc[8][2];
#pragma unroll
    for (int h = 0; h < 8; ++h) { acc[h][0] = 0.f; acc[h][1] = 0.f; }
    for (int n = 0; n < NNB; ++n) {
      float2 x2 = *(const float2*)&nbw[(size_t)n * GG * DIN + 2 * lane];
      const int abase = n * 128 + ((bg * 8) ^ (bl << 3));   // uniform -> broadcast
      f32x4 a0 = *(const f32x4*)&attw[abase];
      f32x4 a1 = *(const f32x4*)&attw[abase + 4];
#pragma unroll
      for (int h = 0; h < 4; ++h) {
        acc[h][0] = fmaf(a0[h], x2.x, acc[h][0]);
        acc[h][1] = fmaf(a0[h], x2.y, acc[h][1]);
        acc[h + 4][0] = fmaf(a1[h], x2.x, acc[h + 4][0]);
        acc[h + 4][1] = fmaf(a1[h], x2.y, acc[h + 4][1]);
      }
    }
    const int swz = (bg & 7) << 4;
#pragma unroll
    for (int h = 0; h < 8; ++h) {
      unsigned pack = (unsigned)f2bf(acc[h][0]) | ((unsigned)f2bf(acc[h][1]) << 16);
      *(unsigned*)(aggb + ((bg * 2048 + h * 256 + 4 * lane) ^ swz)) = pack;
    }
  }
  __syncthreads();   // agg complete; f/att dead -> hb reuse

  // ======== phase B: head transform, wave w -> hh = w; h stored bf16 ========
  {
    const int hh = w;
    const int aswz = (m & 7) << 4;
    bf16x8 a[4];
#pragma unroll
    for (int kb = 0; kb < 4; ++kb)
      a[kb] = *(const bf16x8*)(aggb + ((m * 2048 + hh * 256 + kb * 64 + kg * 16) ^ aswz));
#pragma unroll
    for (int nt = 0; nt < 4; ++nt) {
      f32x4 c = {0.f, 0.f, 0.f, 0.f};
#pragma unroll
      for (int kb = 0; kb < 4; ++kb) {
        const int fi = (((hh * 4 + nt) * 4 + kb) * 64 + lane) * 8;
        bf16x8 bh = *(const bf16x8*)(WBhi + fi);
        bf16x8 bl_ = *(const bf16x8*)(WBlo + fi);
        c = __builtin_amdgcn_mfma_f32_16x16x32_bf16(a[kb], bh, c, 0, 0, 0);
        c = __builtin_amdgcn_mfma_f32_16x16x32_bf16(a[kb], bl_, c, 0, 0, 0);
      }
      const int k = hh * 64 + nt * 16 + m;
#pragma unroll
      for (int reg = 0; reg < 4; ++reg) {
        int row = kg * 4 + reg;
        int byte = (row * 1024 + k * 2) ^ ((row & 7) << 4);
        *(unsigned short*)(hb + byte) = f2bf(lrelu_f(c[reg]));
      }
    }
  }
  __syncthreads();

  // ======== phase C: final FC, waves 0..3, nt = w ========
  if (w < 4) {
    const int nt = w;
    f32x4 acc = {0.f, 0.f, 0.f, 0.f};
    for (int kb = 0; kb < 16; ++kb) {
      int byte = (m * 1024 + (kb * 32 + kg * 8) * 2) ^ ((m & 7) << 4);
      bf16x8 ah = *(const bf16x8*)(hb + byte);
      const int fi = ((nt * 16 + kb) * 64 + lane) * 8;
      bf16x8 bh = *(const bf16x8*)(WOhi + fi);
      bf16x8 bl_ = *(const bf16x8*)(WOlo + fi);
      acc = __builtin_amdgcn_mfma_f32_16x16x32_bf16(ah, bh, acc, 0, 0, 0);
      acc = __builtin_amdgcn_mfma_f32_16x16x32_bf16(ah, bl_, acc, 0, 0, 0);
    }
    const int rbase = bid * 16;
#pragma unroll
    for (int reg = 0; reg < 4; ++reg) {
      int row = rbase + kg * 4 + reg;
      out[(size_t)row * EE + nt * 16 + m] = fmaxf(acc[reg], 0.f);
    }
  }
}

extern "C" void kernel_launch(void* const* d_in, const int* in_sizes, int n_in,
                              void* d_out, int out_size, void* d_ws, size_t ws_size,
                              hipStream_t stream) {
  (void)in_sizes; (void)n_in; (void)out_size; (void)ws_size;
  const float* self_vecs  = (const float*)d_in[0];
  const float* neigh_vecs = (const float*)d_in[1];
  const float* W_heads    = (const float*)d_in[2];
  const float* a_self     = (const float*)d_in[3];
  const float* a_neigh    = (const float*)d_in[4];
  const float* W_out      = (const float*)d_in[5];
  float* out              = (float*)d_out;

  char* ws = (char*)d_ws;
  unsigned short* P1Whi = (unsigned short*)ws;                    // 4 KB
  unsigned short* P1Wlo = (unsigned short*)(ws + 4096);           // 4 KB
  unsigned short* WBhi  = (unsigned short*)(ws + 8192);           // 128 KB
  unsigned short* WBlo  = (unsigned short*)(ws + 8192 + 131072);
  unsigned short* WOhi  = (unsigned short*)(ws + 8192 + 262144);  // 64 KB
  unsigned short* WOlo  = (unsigned short*)(ws + 8192 + 262144 + 65536);

  prep_kernel<<<(2048 + 65536 + 32768) / 256, 256, 0, stream>>>(
      W_heads, a_self, a_neigh, W_out, P1Whi, P1Wlo, WBhi, WBlo, WOhi, WOlo);

  fused_kernel<<<BB / 4, 512, 0, stream>>>(
      self_vecs, neigh_vecs, P1Whi, P1Wlo, WBhi, WBlo, WOhi, WOlo, out);
}

// Round 11
// 76.447 us; speedup vs baseline: 1.0830x; 1.0830x over previous
//
#include <hip/hip_runtime.h>
#include <hip/hip_bf16.h>

#define BB 4096
#define NNB 20
#define GG 4
#define DIN 128
#define EE 64
#define HH 8

typedef short bf16x8 __attribute__((ext_vector_type(8)));
typedef float f32x4 __attribute__((ext_vector_type(4)));

__device__ __forceinline__ float lrelu_f(float x) { return x > 0.f ? x : 0.2f * x; }
__device__ __forceinline__ unsigned short f2bf(float f) {
  unsigned u = __float_as_uint(f);
  return (unsigned short)((u + 0x7fffu + ((u >> 16) & 1u)) >> 16);
}
__device__ __forceinline__ float bf2f(unsigned short s) {
  return __uint_as_float(((unsigned)s) << 16);
}

// ---------------- K0: prep (unchanged) ----------------
__global__ __launch_bounds__(256) void prep_kernel(
    const float* __restrict__ W_heads, const float* __restrict__ a_self,
    const float* __restrict__ a_neigh, const float* __restrict__ W_out,
    unsigned short* __restrict__ P1Whi, unsigned short* __restrict__ P1Wlo,
    unsigned short* __restrict__ WBhi, unsigned short* __restrict__ WBlo,
    unsigned short* __restrict__ WOhi, unsigned short* __restrict__ WOlo) {
  int id = blockIdx.x * 256 + threadIdx.x;
  if (id < 2048) {
    int j = id & 7, lane = (id >> 3) & 63, kb = id >> 9;
    int col = lane & 15, k = kb * 32 + (lane >> 4) * 8 + j;
    int h = col & 7;
    const float* a = (col < 8) ? a_neigh : a_self;
    const float* Wrow = W_heads + (h * DIN + k) * EE;
    float acc = 0.f;
    for (int e = 0; e < EE; ++e) acc = fmaf(Wrow[e], a[h * EE + e], acc);
    unsigned short hi = f2bf(acc);
    P1Whi[id] = hi;
    P1Wlo[id] = f2bf(acc - bf2f(hi));
  } else if (id < 2048 + 65536) {
    int rel = id - 2048;   // (((h*4+nt)*4+kb)*64 + l)*8 + j
    int j = rel & 7, l = (rel >> 3) & 63, kb = (rel >> 9) & 3, nt = (rel >> 11) & 3, h = rel >> 13;
    int d = kb * 32 + (l >> 4) * 8 + j;
    int e = nt * 16 + (l & 15);
    float w = W_heads[(h * DIN + d) * EE + e];
    unsigned short hi = f2bf(w);
    WBhi[rel] = hi;
    WBlo[rel] = f2bf(w - bf2f(hi));
  } else if (id < 2048 + 65536 + 32768) {
    int rel = id - 2048 - 65536;  // ((nt*16+kb)*64 + l)*8 + j
    int j = rel & 7, l = (rel >> 3) & 63, kb = (rel >> 9) & 15, nt = rel >> 13;
    int k = kb * 32 + (l >> 4) * 8 + j;
    int n = nt * 16 + (l & 15);
    float w = W_out[k * EE + n];
    unsigned short hi = f2bf(w);
    WOhi[rel] = hi;
    WOlo[rel] = f2bf(w - bf2f(hi));
  }
}

// ---------------- Fused kernel: 512 threads (8 waves), 4 b's = 16 bg rows ----------------
// LDS 49,152 B:
//   [0,32768):       P1-phase: wf staging [0,8192) (hi then lo). P3+: agg bf16
//                    [bg16][h8][d128], byte ^ ((bg&7)<<4).
//   [32768,49152):   P1-P3: att f32, word = n*128 + bg*8 + h   (10,240 B used)
//                    B-C:   h bf16 [row16][k512], byte ^ ((row&7)<<4) (16,384 B)
// Softmax is IN-LANE: after a tile's MFMA, lane (m<8, kg) holds f_n[bg=kg*4+reg][h=m]
// in c[reg]; self-f comes from a per-wave redundant self tile + shfl_xor(8).
__global__ __launch_bounds__(512, 6) void fused_kernel(
    const float* __restrict__ self_vecs, const float* __restrict__ neigh_vecs,
    const unsigned short* __restrict__ P1Whi, const unsigned short* __restrict__ P1Wlo,
    const unsigned short* __restrict__ WBhi, const unsigned short* __restrict__ WBlo,
    const unsigned short* __restrict__ WOhi, const unsigned short* __restrict__ WOlo,
    float* __restrict__ out) {
  __shared__ char smem[49152];
  char* aggb = smem;                       // agg after P1; wf staging during P1
  float* attw = (float*)(smem + 32768);    // att words (P1..P3)
  char* hb = smem + 32768;                 // h bytes (B..C)

  const int t = threadIdx.x;
  const int w = t >> 6, lane = t & 63;
  const int m = lane & 15, kg = lane >> 4;
  const int bid = blockIdx.x;

  // stage P1 weight frags into LDS [0,8192)
  if (t < 512) {
    const float4* src = (t < 256) ? (const float4*)P1Whi : (const float4*)P1Wlo;
    ((float4*)smem)[t] = src[t & 255];
  }
  __syncthreads();

  // ---- helper lambda-ish macro: one P1 tile MFMA into c ----
#define P1_TILE(rowp, cvec)                                                    \
  {                                                                            \
    _Pragma("unroll") for (int kb = 0; kb < 4; ++kb) {                         \
      float4 xa = *(const float4*)((rowp) + kb * 32 + kg * 8);                 \
      float4 xb = *(const float4*)((rowp) + kb * 32 + kg * 8 + 4);             \
      float xv[8] = {xa.x, xa.y, xa.z, xa.w, xb.x, xb.y, xb.z, xb.w};          \
      bf16x8 xh, xl;                                                           \
      _Pragma("unroll") for (int j = 0; j < 8; ++j) {                          \
        unsigned short hi = f2bf(xv[j]);                                       \
        xh[j] = (short)hi;                                                     \
        xl[j] = (short)f2bf(xv[j] - bf2f(hi));                                 \
      }                                                                        \
      bf16x8 wh = *(const bf16x8*)(smem + kb * 1024 + lane * 16);              \
      bf16x8 wl = *(const bf16x8*)(smem + 4096 + kb * 1024 + lane * 16);       \
      cvec = __builtin_amdgcn_mfma_f32_16x16x32_bf16(xh, wh, cvec, 0, 0, 0);   \
      cvec = __builtin_amdgcn_mfma_f32_16x16x32_bf16(xh, wl, cvec, 0, 0, 0);   \
      cvec = __builtin_amdgcn_mfma_f32_16x16x32_bf16(xl, wh, cvec, 0, 0, 0);   \
    }                                                                          \
  }

  // ======== P1a: self tile (redundant per wave, keeps fs in regs) ========
  f32x4 fs;
  {
    f32x4 c20 = {0.f, 0.f, 0.f, 0.f};
    const float* srow = self_vecs + ((size_t)bid * 16 + m) * DIN;
    P1_TILE(srow, c20)
    // lane (m+8,kg) holds f_self[bg=kg*4+reg][h=m]; pull it down to lanes m<8
#pragma unroll
    for (int reg = 0; reg < 4; ++reg) fs[reg] = __shfl_xor(c20[reg], 8);
  }

  // ======== P1b: n-tiles with in-lane softmax ========
  const int bl_m = m >> 2, g_m = m & 3;
  for (int tile = w; tile < 20; tile += 8) {
    const float* rowp =
        neigh_vecs + (((size_t)(bid * 4 + bl_m) * NNB + tile) * GG + g_m) * DIN;
    f32x4 c = {0.f, 0.f, 0.f, 0.f};
    P1_TILE(rowp, c)
    if (m < 8) {
      float l[4], mx = -1e30f;
#pragma unroll
      for (int gg = 0; gg < 4; ++gg) {
        float v = lrelu_f(fs[gg] + c[gg]);
        l[gg] = v;
        mx = fmaxf(mx, v);
      }
      float s = 0.f;
#pragma unroll
      for (int gg = 0; gg < 4; ++gg) { l[gg] = __expf(l[gg] - mx); s += l[gg]; }
      float inv = 1.f / s;
#pragma unroll
      for (int gg = 0; gg < 4; ++gg)
        attw[tile * 128 + (kg * 4 + gg) * 8 + m] = l[gg] * inv;
    }
  }
  __syncthreads();   // att complete; wf staging dead -> agg region free

  // ======== P3: agg[bg][h][d] = sum_n att*x ; wave w -> bg {2w, 2w+1} ========
#pragma unroll
  for (int i = 0; i < 2; ++i) {
    const int bg = 2 * w + i;
    const int bl = bg >> 2, g = bg & 3;
    const float* nbw = neigh_vecs + ((size_t)(bid * 4 + bl) * NNB * GG + g) * DIN;
    float acc[8][2];
#pragma unroll
    for (int h = 0; h < 8; ++h) { acc[h][0] = 0.f; acc[h][1] = 0.f; }
    for (int n = 0; n < NNB; ++n) {
      float2 x2 = *(const float2*)&nbw[(size_t)n * GG * DIN + 2 * lane];
      f32x4 a0 = *(const f32x4*)&attw[n * 128 + bg * 8];      // uniform -> broadcast
      f32x4 a1 = *(const f32x4*)&attw[n * 128 + bg * 8 + 4];
#pragma unroll
      for (int h = 0; h < 4; ++h) {
        acc[h][0] = fmaf(a0[h], x2.x, acc[h][0]);
        acc[h][1] = fmaf(a0[h], x2.y, acc[h][1]);
        acc[h + 4][0] = fmaf(a1[h], x2.x, acc[h + 4][0]);
        acc[h + 4][1] = fmaf(a1[h], x2.y, acc[h + 4][1]);
      }
    }
    const int swz = (bg & 7) << 4;
#pragma unroll
    for (int h = 0; h < 8; ++h) {
      unsigned pack = (unsigned)f2bf(acc[h][0]) | ((unsigned)f2bf(acc[h][1]) << 16);
      *(unsigned*)(aggb + ((bg * 2048 + h * 256 + 4 * lane) ^ swz)) = pack;
    }
  }
  __syncthreads();   // agg complete; att dead -> hb reuse

  // ======== phase B: head transform, wave w -> hh = w; h stored bf16 ========
  {
    const int hh = w;
    const int aswz = (m & 7) << 4;
    bf16x8 a[4];
#pragma unroll
    for (int kb = 0; kb < 4; ++kb)
      a[kb] = *(const bf16x8*)(aggb + ((m * 2048 + hh * 256 + kb * 64 + kg * 16) ^ aswz));
#pragma unroll
    for (int nt = 0; nt < 4; ++nt) {
      f32x4 c = {0.f, 0.f, 0.f, 0.f};
#pragma unroll
      for (int kb = 0; kb < 4; ++kb) {
        const int fi = (((hh * 4 + nt) * 4 + kb) * 64 + lane) * 8;
        bf16x8 bh = *(const bf16x8*)(WBhi + fi);
        bf16x8 bl_ = *(const bf16x8*)(WBlo + fi);
        c = __builtin_amdgcn_mfma_f32_16x16x32_bf16(a[kb], bh, c, 0, 0, 0);
        c = __builtin_amdgcn_mfma_f32_16x16x32_bf16(a[kb], bl_, c, 0, 0, 0);
      }
      const int k = hh * 64 + nt * 16 + m;
#pragma unroll
      for (int reg = 0; reg < 4; ++reg) {
        int row = kg * 4 + reg;
        int byte = (row * 1024 + k * 2) ^ ((row & 7) << 4);
        *(unsigned short*)(hb + byte) = f2bf(lrelu_f(c[reg]));
      }
    }
  }
  __syncthreads();

  // ======== phase C: final FC, waves 0..3, nt = w ========
  if (w < 4) {
    const int nt = w;
    f32x4 acc = {0.f, 0.f, 0.f, 0.f};
    for (int kb = 0; kb < 16; ++kb) {
      int byte = (m * 1024 + (kb * 32 + kg * 8) * 2) ^ ((m & 7) << 4);
      bf16x8 ah = *(const bf16x8*)(hb + byte);
      const int fi = ((nt * 16 + kb) * 64 + lane) * 8;
      bf16x8 bh = *(const bf16x8*)(WOhi + fi);
      bf16x8 bl_ = *(const bf16x8*)(WOlo + fi);
      acc = __builtin_amdgcn_mfma_f32_16x16x32_bf16(ah, bh, acc, 0, 0, 0);
      acc = __builtin_amdgcn_mfma_f32_16x16x32_bf16(ah, bl_, acc, 0, 0, 0);
    }
    const int rbase = bid * 16;
#pragma unroll
    for (int reg = 0; reg < 4; ++reg) {
      int row = rbase + kg * 4 + reg;
      out[(size_t)row * EE + nt * 16 + m] = fmaxf(acc[reg], 0.f);
    }
  }
#undef P1_TILE
}

extern "C" void kernel_launch(void* const* d_in, const int* in_sizes, int n_in,
                              void* d_out, int out_size, void* d_ws, size_t ws_size,
                              hipStream_t stream) {
  (void)in_sizes; (void)n_in; (void)out_size; (void)ws_size;
  const float* self_vecs  = (const float*)d_in[0];
  const float* neigh_vecs = (const float*)d_in[1];
  const float* W_heads    = (const float*)d_in[2];
  const float* a_self     = (const float*)d_in[3];
  const float* a_neigh    = (const float*)d_in[4];
  const float* W_out      = (const float*)d_in[5];
  float* out              = (float*)d_out;

  char* ws = (char*)d_ws;
  unsigned short* P1Whi = (unsigned short*)ws;                    // 4 KB
  unsigned short* P1Wlo = (unsigned short*)(ws + 4096);           // 4 KB
  unsigned short* WBhi  = (unsigned short*)(ws + 8192);           // 128 KB
  unsigned short* WBlo  = (unsigned short*)(ws + 8192 + 131072);
  unsigned short* WOhi  = (unsigned short*)(ws + 8192 + 262144);  // 64 KB
  unsigned short* WOlo  = (unsigned short*)(ws + 8192 + 262144 + 65536);

  prep_kernel<<<(2048 + 65536 + 32768) / 256, 256, 0, stream>>>(
      W_heads, a_self, a_neigh, W_out, P1Whi, P1Wlo, WBhi, WBlo, WOhi, WOlo);

  fused_kernel<<<BB / 4, 512, 0, stream>>>(
      self_vecs, neigh_vecs, P1Whi, P1Wlo, WBhi, WBlo, WOhi, WOlo, out);
}

// Round 12
// 72.410 us; speedup vs baseline: 1.1433x; 1.0557x over previous
//
#include <hip/hip_runtime.h>
#include <hip/hip_bf16.h>

#define BB 4096
#define NNB 20
#define GG 4
#define DIN 128
#define EE 64
#define HH 8

typedef short bf16x8 __attribute__((ext_vector_type(8)));
typedef float f32x4 __attribute__((ext_vector_type(4)));

__device__ __forceinline__ float lrelu_f(float x) { return x > 0.f ? x : 0.2f * x; }
__device__ __forceinline__ unsigned short f2bf(float f) {
  unsigned u = __float_as_uint(f);
  return (unsigned short)((u + 0x7fffu + ((u >> 16) & 1u)) >> 16);
}
__device__ __forceinline__ float bf2f(unsigned short s) {
  return __uint_as_float(((unsigned)s) << 16);
}

// ---------------- K0: prep (unchanged) ----------------
__global__ __launch_bounds__(256) void prep_kernel(
    const float* __restrict__ W_heads, const float* __restrict__ a_self,
    const float* __restrict__ a_neigh, const float* __restrict__ W_out,
    unsigned short* __restrict__ P1Whi, unsigned short* __restrict__ P1Wlo,
    unsigned short* __restrict__ WBhi, unsigned short* __restrict__ WBlo,
    unsigned short* __restrict__ WOhi, unsigned short* __restrict__ WOlo) {
  int id = blockIdx.x * 256 + threadIdx.x;
  if (id < 2048) {
    int j = id & 7, lane = (id >> 3) & 63, kb = id >> 9;
    int col = lane & 15, k = kb * 32 + (lane >> 4) * 8 + j;
    int h = col & 7;
    const float* a = (col < 8) ? a_neigh : a_self;
    const float* Wrow = W_heads + (h * DIN + k) * EE;
    float acc = 0.f;
    for (int e = 0; e < EE; ++e) acc = fmaf(Wrow[e], a[h * EE + e], acc);
    unsigned short hi = f2bf(acc);
    P1Whi[id] = hi;
    P1Wlo[id] = f2bf(acc - bf2f(hi));
  } else if (id < 2048 + 65536) {
    int rel = id - 2048;   // (((h*4+nt)*4+kb)*64 + l)*8 + j
    int j = rel & 7, l = (rel >> 3) & 63, kb = (rel >> 9) & 3, nt = (rel >> 11) & 3, h = rel >> 13;
    int d = kb * 32 + (l >> 4) * 8 + j;
    int e = nt * 16 + (l & 15);
    float w = W_heads[(h * DIN + d) * EE + e];
    unsigned short hi = f2bf(w);
    WBhi[rel] = hi;
    WBlo[rel] = f2bf(w - bf2f(hi));
  } else if (id < 2048 + 65536 + 32768) {
    int rel = id - 2048 - 65536;  // ((nt*16+kb)*64 + l)*8 + j
    int j = rel & 7, l = (rel >> 3) & 63, kb = (rel >> 9) & 15, nt = rel >> 13;
    int k = kb * 32 + (l >> 4) * 8 + j;
    int n = nt * 16 + (l & 15);
    float w = W_out[k * EE + n];
    unsigned short hi = f2bf(w);
    WOhi[rel] = hi;
    WOlo[rel] = f2bf(w - bf2f(hi));
  }
}

// ---------------- Fused kernel: 512 threads (8 waves), 4 b's = 16 bg rows ----------------
// LDS 49,152 B:
//   [0,32768):     agg bf16 [bg16][h8][d128], byte ^ ((bg&7)<<4)   (written in P3)
//   [32768,49152): P1-P3: att f32, word = n*128 + bg*8 + h (10,240 B used)
//                  B-C:   h bf16 [row16][k512], byte ^ ((row&7)<<4) (16,384 B)
// In-lane softmax: after tile MFMA, lane (m<8, kg) holds f_n[bg=kg*4+reg][h=m];
// self-f from redundant per-wave self tile + shfl_xor(8). 3 barriers total.
__global__ __launch_bounds__(512, 4) void fused_kernel(
    const float* __restrict__ self_vecs, const float* __restrict__ neigh_vecs,
    const unsigned short* __restrict__ P1Whi, const unsigned short* __restrict__ P1Wlo,
    const unsigned short* __restrict__ WBhi, const unsigned short* __restrict__ WBlo,
    const unsigned short* __restrict__ WOhi, const unsigned short* __restrict__ WOlo,
    float* __restrict__ out) {
  __shared__ char smem[49152];
  char* aggb = smem;
  float* attw = (float*)(smem + 32768);
  char* hb = smem + 32768;

  const int t = threadIdx.x;
  const int w = t >> 6, lane = t & 63;
  const int m = lane & 15, kg = lane >> 4;
  const int bid = blockIdx.x;

  // P1 weight frags in registers (B operand, constant across tiles)
  bf16x8 wfh[4], wfl[4];
#pragma unroll
  for (int kb = 0; kb < 4; ++kb) {
    wfh[kb] = *(const bf16x8*)(P1Whi + (kb * 64 + lane) * 8);
    wfl[kb] = *(const bf16x8*)(P1Wlo + (kb * 64 + lane) * 8);
  }

#define P1_TILE(rowp, cvec)                                                    \
  {                                                                            \
    _Pragma("unroll") for (int kb = 0; kb < 4; ++kb) {                         \
      float4 xa = *(const float4*)((rowp) + kb * 32 + kg * 8);                 \
      float4 xb = *(const float4*)((rowp) + kb * 32 + kg * 8 + 4);             \
      float xv[8] = {xa.x, xa.y, xa.z, xa.w, xb.x, xb.y, xb.z, xb.w};          \
      bf16x8 xh, xl;                                                           \
      _Pragma("unroll") for (int j = 0; j < 8; ++j) {                          \
        unsigned short hi = f2bf(xv[j]);                                       \
        xh[j] = (short)hi;                                                     \
        xl[j] = (short)f2bf(xv[j] - bf2f(hi));                                 \
      }                                                                        \
      cvec = __builtin_amdgcn_mfma_f32_16x16x32_bf16(xh, wfh[kb], cvec, 0, 0, 0); \
      cvec = __builtin_amdgcn_mfma_f32_16x16x32_bf16(xh, wfl[kb], cvec, 0, 0, 0); \
      cvec = __builtin_amdgcn_mfma_f32_16x16x32_bf16(xl, wfh[kb], cvec, 0, 0, 0); \
    }                                                                          \
  }

  // ======== P1a: self tile (redundant per wave, keeps fs in regs) ========
  f32x4 fs;
  {
    f32x4 c20 = {0.f, 0.f, 0.f, 0.f};
    const float* srow = self_vecs + ((size_t)bid * 16 + m) * DIN;
    P1_TILE(srow, c20)
#pragma unroll
    for (int reg = 0; reg < 4; ++reg) fs[reg] = __shfl_xor(c20[reg], 8);
  }

  // ======== P1b: n-tiles with in-lane softmax ========
  const int bl_m = m >> 2, g_m = m & 3;
  for (int tile = w; tile < 20; tile += 8) {
    const float* rowp =
        neigh_vecs + (((size_t)(bid * 4 + bl_m) * NNB + tile) * GG + g_m) * DIN;
    f32x4 c = {0.f, 0.f, 0.f, 0.f};
    P1_TILE(rowp, c)
    if (m < 8) {
      float l[4], mx = -1e30f;
#pragma unroll
      for (int gg = 0; gg < 4; ++gg) {
        float v = lrelu_f(fs[gg] + c[gg]);
        l[gg] = v;
        mx = fmaxf(mx, v);
      }
      float s = 0.f;
#pragma unroll
      for (int gg = 0; gg < 4; ++gg) { l[gg] = __expf(l[gg] - mx); s += l[gg]; }
      float inv = 1.f / s;
#pragma unroll
      for (int gg = 0; gg < 4; ++gg)
        attw[tile * 128 + (kg * 4 + gg) * 8 + m] = l[gg] * inv;
    }
  }
  __syncthreads();   // att complete

  // ======== P3: agg[bg][h][d] = sum_n att*x ; wave w -> bg {2w, 2w+1} ========
#pragma unroll
  for (int i = 0; i < 2; ++i) {
    const int bg = 2 * w + i;
    const int bl = bg >> 2, g = bg & 3;
    const float* nbw = neigh_vecs + ((size_t)(bid * 4 + bl) * NNB * GG + g) * DIN;
    float acc[8][2];
#pragma unroll
    for (int h = 0; h < 8; ++h) { acc[h][0] = 0.f; acc[h][1] = 0.f; }
    for (int n = 0; n < NNB; ++n) {
      float2 x2 = *(const float2*)&nbw[(size_t)n * GG * DIN + 2 * lane];
      f32x4 a0 = *(const f32x4*)&attw[n * 128 + bg * 8];      // uniform -> broadcast
      f32x4 a1 = *(const f32x4*)&attw[n * 128 + bg * 8 + 4];
#pragma unroll
      for (int h = 0; h < 4; ++h) {
        acc[h][0] = fmaf(a0[h], x2.x, acc[h][0]);
        acc[h][1] = fmaf(a0[h], x2.y, acc[h][1]);
        acc[h + 4][0] = fmaf(a1[h], x2.x, acc[h + 4][0]);
        acc[h + 4][1] = fmaf(a1[h], x2.y, acc[h + 4][1]);
      }
    }
    const int swz = (bg & 7) << 4;
#pragma unroll
    for (int h = 0; h < 8; ++h) {
      unsigned pack = (unsigned)f2bf(acc[h][0]) | ((unsigned)f2bf(acc[h][1]) << 16);
      *(unsigned*)(aggb + ((bg * 2048 + h * 256 + 4 * lane) ^ swz)) = pack;
    }
  }
  __syncthreads();   // agg complete; att dead -> hb reuse

  // ======== phase B: head transform, wave w -> hh = w; h stored bf16 ========
  {
    const int hh = w;
    const int aswz = (m & 7) << 4;
    bf16x8 a[4];
#pragma unroll
    for (int kb = 0; kb < 4; ++kb)
      a[kb] = *(const bf16x8*)(aggb + ((m * 2048 + hh * 256 + kb * 64 + kg * 16) ^ aswz));
#pragma unroll
    for (int nt = 0; nt < 4; ++nt) {
      f32x4 c = {0.f, 0.f, 0.f, 0.f};
#pragma unroll
      for (int kb = 0; kb < 4; ++kb) {
        const int fi = (((hh * 4 + nt) * 4 + kb) * 64 + lane) * 8;
        bf16x8 bh = *(const bf16x8*)(WBhi + fi);
        bf16x8 bl_ = *(const bf16x8*)(WBlo + fi);
        c = __builtin_amdgcn_mfma_f32_16x16x32_bf16(a[kb], bh, c, 0, 0, 0);
        c = __builtin_amdgcn_mfma_f32_16x16x32_bf16(a[kb], bl_, c, 0, 0, 0);
      }
      const int k = hh * 64 + nt * 16 + m;
#pragma unroll
      for (int reg = 0; reg < 4; ++reg) {
        int row = kg * 4 + reg;
        int byte = (row * 1024 + k * 2) ^ ((row & 7) << 4);
        *(unsigned short*)(hb + byte) = f2bf(lrelu_f(c[reg]));
      }
    }
  }
  __syncthreads();

  // ======== phase C: final FC, waves 0..3, nt = w ========
  if (w < 4) {
    const int nt = w;
    f32x4 acc = {0.f, 0.f, 0.f, 0.f};
    for (int kb = 0; kb < 16; ++kb) {
      int byte = (m * 1024 + (kb * 32 + kg * 8) * 2) ^ ((m & 7) << 4);
      bf16x8 ah = *(const bf16x8*)(hb + byte);
      const int fi = ((nt * 16 + kb) * 64 + lane) * 8;
      bf16x8 bh = *(const bf16x8*)(WOhi + fi);
      bf16x8 bl_ = *(const bf16x8*)(WOlo + fi);
      acc = __builtin_amdgcn_mfma_f32_16x16x32_bf16(ah, bh, acc, 0, 0, 0);
      acc = __builtin_amdgcn_mfma_f32_16x16x32_bf16(ah, bl_, acc, 0, 0, 0);
    }
    const int rbase = bid * 16;
#pragma unroll
    for (int reg = 0; reg < 4; ++reg) {
      int row = rbase + kg * 4 + reg;
      out[(size_t)row * EE + nt * 16 + m] = fmaxf(acc[reg], 0.f);
    }
  }
#undef P1_TILE
}

extern "C" void kernel_launch(void* const* d_in, const int* in_sizes, int n_in,
                              void* d_out, int out_size, void* d_ws, size_t ws_size,
                              hipStream_t stream) {
  (void)in_sizes; (void)n_in; (void)out_size; (void)ws_size;
  const float* self_vecs  = (const float*)d_in[0];
  const float* neigh_vecs = (const float*)d_in[1];
  const float* W_heads    = (const float*)d_in[2];
  const float* a_self     = (const float*)d_in[3];
  const float* a_neigh    = (const float*)d_in[4];
  const float* W_out      = (const float*)d_in[5];
  float* out              = (float*)d_out;

  char* ws = (char*)d_ws;
  unsigned short* P1Whi = (unsigned short*)ws;                    // 4 KB
  unsigned short* P1Wlo = (unsigned short*)(ws + 4096);           // 4 KB
  unsigned short* WBhi  = (unsigned short*)(ws + 8192);           // 128 KB
  unsigned short* WBlo  = (unsigned short*)(ws + 8192 + 131072);
  unsigned short* WOhi  = (unsigned short*)(ws + 8192 + 262144);  // 64 KB
  unsigned short* WOlo  = (unsigned short*)(ws + 8192 + 262144 + 65536);

  prep_kernel<<<(2048 + 65536 + 32768) / 256, 256, 0, stream>>>(
      W_heads, a_self, a_neigh, W_out, P1Whi, P1Wlo, WBhi, WBlo, WOhi, WOlo);

  fused_kernel<<<BB / 4, 512, 0, stream>>>(
      self_vecs, neigh_vecs, P1Whi, P1Wlo, WBhi, WBlo, WOhi, WOlo, out);
}

// Round 13
// 72.220 us; speedup vs baseline: 1.1463x; 1.0026x over previous
//
#include <hip/hip_runtime.h>
#include <hip/hip_bf16.h>

#define BB 4096
#define NNB 20
#define GG 4
#define DIN 128
#define EE 64
#define HH 8

typedef short bf16x8 __attribute__((ext_vector_type(8)));
typedef float f32x4 __attribute__((ext_vector_type(4)));

__device__ __forceinline__ float lrelu_f(float x) { return x > 0.f ? x : 0.2f * x; }
__device__ __forceinline__ unsigned short f2bf(float f) {
  unsigned u = __float_as_uint(f);
  return (unsigned short)((u + 0x7fffu + ((u >> 16) & 1u)) >> 16);
}
__device__ __forceinline__ float bf2f(unsigned short s) {
  return __uint_as_float(((unsigned)s) << 16);
}

// ---------------- K0: prep (unchanged) ----------------
__global__ __launch_bounds__(256) void prep_kernel(
    const float* __restrict__ W_heads, const float* __restrict__ a_self,
    const float* __restrict__ a_neigh, const float* __restrict__ W_out,
    unsigned short* __restrict__ P1Whi, unsigned short* __restrict__ P1Wlo,
    unsigned short* __restrict__ WBhi, unsigned short* __restrict__ WBlo,
    unsigned short* __restrict__ WOhi, unsigned short* __restrict__ WOlo) {
  int id = blockIdx.x * 256 + threadIdx.x;
  if (id < 2048) {
    int j = id & 7, lane = (id >> 3) & 63, kb = id >> 9;
    int col = lane & 15, k = kb * 32 + (lane >> 4) * 8 + j;
    int h = col & 7;
    const float* a = (col < 8) ? a_neigh : a_self;
    const float* Wrow = W_heads + (h * DIN + k) * EE;
    float acc = 0.f;
    for (int e = 0; e < EE; ++e) acc = fmaf(Wrow[e], a[h * EE + e], acc);
    unsigned short hi = f2bf(acc);
    P1Whi[id] = hi;
    P1Wlo[id] = f2bf(acc - bf2f(hi));
  } else if (id < 2048 + 65536) {
    int rel = id - 2048;   // (((h*4+nt)*4+kb)*64 + l)*8 + j
    int j = rel & 7, l = (rel >> 3) & 63, kb = (rel >> 9) & 3, nt = (rel >> 11) & 3, h = rel >> 13;
    int d = kb * 32 + (l >> 4) * 8 + j;
    int e = nt * 16 + (l & 15);
    float w = W_heads[(h * DIN + d) * EE + e];
    unsigned short hi = f2bf(w);
    WBhi[rel] = hi;
    WBlo[rel] = f2bf(w - bf2f(hi));
  } else if (id < 2048 + 65536 + 32768) {
    int rel = id - 2048 - 65536;  // ((nt*16+kb)*64 + l)*8 + j
    int j = rel & 7, l = (rel >> 3) & 63, kb = (rel >> 9) & 15, nt = rel >> 13;
    int k = kb * 32 + (l >> 4) * 8 + j;
    int n = nt * 16 + (l & 15);
    float w = W_out[k * EE + n];
    unsigned short hi = f2bf(w);
    WOhi[rel] = hi;
    WOlo[rel] = f2bf(w - bf2f(hi));
  }
}

// ---------------- Fused kernel: 512 threads (8 waves), 4 b's = 16 bg rows ----------------
// LDS padded to 57,344 B so only 2 blocks/CU fit -> scheduler targets 4 waves/EU
// -> full 128-VGPR budget (R12's 3-block/85-reg target starved ILP at VGPR=52).
//   [0,32768):     agg bf16 [bg16][h8][d128], byte ^ ((bg&7)<<4)   (written in P3)
//   [32768,49152): P1-P3: att f32, word = n*128 + bg*8 + h (10,240 B used)
//                  B-C:   h bf16 [row16][k512], byte ^ ((row&7)<<4) (16,384 B)
//   [49152,57344): pad (occupancy control)
__global__ __launch_bounds__(512, 4) void fused_kernel(
    const float* __restrict__ self_vecs, const float* __restrict__ neigh_vecs,
    const unsigned short* __restrict__ P1Whi, const unsigned short* __restrict__ P1Wlo,
    const unsigned short* __restrict__ WBhi, const unsigned short* __restrict__ WBlo,
    const unsigned short* __restrict__ WOhi, const unsigned short* __restrict__ WOlo,
    float* __restrict__ out) {
  __shared__ char smem[57344];
  char* aggb = smem;
  float* attw = (float*)(smem + 32768);
  char* hb = smem + 32768;

  const int t = threadIdx.x;
  const int w = t >> 6, lane = t & 63;
  const int m = lane & 15, kg = lane >> 4;
  const int bid = blockIdx.x;

  // P1 weight frags in registers (B operand, constant across tiles)
  bf16x8 wfh[4], wfl[4];
#pragma unroll
  for (int kb = 0; kb < 4; ++kb) {
    wfh[kb] = *(const bf16x8*)(P1Whi + (kb * 64 + lane) * 8);
    wfl[kb] = *(const bf16x8*)(P1Wlo + (kb * 64 + lane) * 8);
  }

#define P1_TILE(rowp, cvec)                                                    \
  {                                                                            \
    _Pragma("unroll") for (int kb = 0; kb < 4; ++kb) {                         \
      float4 xa = *(const float4*)((rowp) + kb * 32 + kg * 8);                 \
      float4 xb = *(const float4*)((rowp) + kb * 32 + kg * 8 + 4);             \
      float xv[8] = {xa.x, xa.y, xa.z, xa.w, xb.x, xb.y, xb.z, xb.w};          \
      bf16x8 xh, xl;                                                           \
      _Pragma("unroll") for (int j = 0; j < 8; ++j) {                          \
        unsigned short hi = f2bf(xv[j]);                                       \
        xh[j] = (short)hi;                                                     \
        xl[j] = (short)f2bf(xv[j] - bf2f(hi));                                 \
      }                                                                        \
      cvec = __builtin_amdgcn_mfma_f32_16x16x32_bf16(xh, wfh[kb], cvec, 0, 0, 0); \
      cvec = __builtin_amdgcn_mfma_f32_16x16x32_bf16(xh, wfl[kb], cvec, 0, 0, 0); \
      cvec = __builtin_amdgcn_mfma_f32_16x16x32_bf16(xl, wfh[kb], cvec, 0, 0, 0); \
    }                                                                          \
  }

#define P1_SOFTMAX(tile, cvec)                                                 \
  if (m < 8) {                                                                 \
    float l[4], mx = -1e30f;                                                   \
    _Pragma("unroll") for (int gg = 0; gg < 4; ++gg) {                         \
      float v = lrelu_f(fs[gg] + (cvec)[gg]);                                  \
      l[gg] = v;                                                               \
      mx = fmaxf(mx, v);                                                       \
    }                                                                          \
    float s = 0.f;                                                             \
    _Pragma("unroll") for (int gg = 0; gg < 4; ++gg) {                         \
      l[gg] = __expf(l[gg] - mx);                                              \
      s += l[gg];                                                              \
    }                                                                          \
    float inv = 1.f / s;                                                       \
    _Pragma("unroll") for (int gg = 0; gg < 4; ++gg)                           \
      attw[(tile) * 128 + (kg * 4 + gg) * 8 + m] = l[gg] * inv;                \
  }

  // ======== P1a: self tile (redundant per wave, keeps fs in regs) ========
  f32x4 fs;
  {
    f32x4 c20 = {0.f, 0.f, 0.f, 0.f};
    const float* srow = self_vecs + ((size_t)bid * 16 + m) * DIN;
    P1_TILE(srow, c20)
#pragma unroll
    for (int reg = 0; reg < 4; ++reg) fs[reg] = __shfl_xor(c20[reg], 8);
  }

  // ======== P1b: n-tiles (straight-line: w, w+8, guarded w+16) ========
  const int bl_m = m >> 2, g_m = m & 3;
  const float* base_n =
      neigh_vecs + ((size_t)(bid * 4 + bl_m) * NNB * GG + g_m) * DIN;
  {
    f32x4 cA = {0.f, 0.f, 0.f, 0.f}, cB = {0.f, 0.f, 0.f, 0.f};
    const float* rpA = base_n + (size_t)w * (GG * DIN);
    const float* rpB = base_n + (size_t)(w + 8) * (GG * DIN);
    P1_TILE(rpA, cA)
    P1_TILE(rpB, cB)
    if (w < 4) {
      f32x4 cC = {0.f, 0.f, 0.f, 0.f};
      const float* rpC = base_n + (size_t)(w + 16) * (GG * DIN);
      P1_TILE(rpC, cC)
      P1_SOFTMAX(w + 16, cC)
    }
    P1_SOFTMAX(w, cA)
    P1_SOFTMAX(w + 8, cB)
  }
  __syncthreads();   // att complete

  // ======== P3: agg[bg][h][d] = sum_n att*x ; wave w -> bg {2w, 2w+1} ========
#pragma unroll
  for (int i = 0; i < 2; ++i) {
    const int bg = 2 * w + i;
    const int bl = bg >> 2, g = bg & 3;
    const float* nbw = neigh_vecs + ((size_t)(bid * 4 + bl) * NNB * GG + g) * DIN;
    float acc[8][2];
#pragma unroll
    for (int h = 0; h < 8; ++h) { acc[h][0] = 0.f; acc[h][1] = 0.f; }
#pragma unroll
    for (int n = 0; n < NNB; ++n) {
      float2 x2 = *(const float2*)&nbw[(size_t)n * GG * DIN + 2 * lane];
      f32x4 a0 = *(const f32x4*)&attw[n * 128 + bg * 8];      // uniform -> broadcast
      f32x4 a1 = *(const f32x4*)&attw[n * 128 + bg * 8 + 4];
#pragma unroll
      for (int h = 0; h < 4; ++h) {
        acc[h][0] = fmaf(a0[h], x2.x, acc[h][0]);
        acc[h][1] = fmaf(a0[h], x2.y, acc[h][1]);
        acc[h + 4][0] = fmaf(a1[h], x2.x, acc[h + 4][0]);
        acc[h + 4][1] = fmaf(a1[h], x2.y, acc[h + 4][1]);
      }
    }
    const int swz = (bg & 7) << 4;
#pragma unroll
    for (int h = 0; h < 8; ++h) {
      unsigned pack = (unsigned)f2bf(acc[h][0]) | ((unsigned)f2bf(acc[h][1]) << 16);
      *(unsigned*)(aggb + ((bg * 2048 + h * 256 + 4 * lane) ^ swz)) = pack;
    }
  }
  __syncthreads();   // agg complete; att dead -> hb reuse

  // ======== phase B: head transform, wave w -> hh = w; h stored bf16 ========
  {
    const int hh = w;
    const int aswz = (m & 7) << 4;
    bf16x8 a[4];
#pragma unroll
    for (int kb = 0; kb < 4; ++kb)
      a[kb] = *(const bf16x8*)(aggb + ((m * 2048 + hh * 256 + kb * 64 + kg * 16) ^ aswz));
#pragma unroll
    for (int nt = 0; nt < 4; ++nt) {
      f32x4 c = {0.f, 0.f, 0.f, 0.f};
#pragma unroll
      for (int kb = 0; kb < 4; ++kb) {
        const int fi = (((hh * 4 + nt) * 4 + kb) * 64 + lane) * 8;
        bf16x8 bh = *(const bf16x8*)(WBhi + fi);
        bf16x8 bl_ = *(const bf16x8*)(WBlo + fi);
        c = __builtin_amdgcn_mfma_f32_16x16x32_bf16(a[kb], bh, c, 0, 0, 0);
        c = __builtin_amdgcn_mfma_f32_16x16x32_bf16(a[kb], bl_, c, 0, 0, 0);
      }
      const int k = hh * 64 + nt * 16 + m;
#pragma unroll
      for (int reg = 0; reg < 4; ++reg) {
        int row = kg * 4 + reg;
        int byte = (row * 1024 + k * 2) ^ ((row & 7) << 4);
        *(unsigned short*)(hb + byte) = f2bf(lrelu_f(c[reg]));
      }
    }
  }
  __syncthreads();

  // ======== phase C: final FC, waves 0..3, nt = w ========
  if (w < 4) {
    const int nt = w;
    f32x4 acc = {0.f, 0.f, 0.f, 0.f};
    for (int kb = 0; kb < 16; ++kb) {
      int byte = (m * 1024 + (kb * 32 + kg * 8) * 2) ^ ((m & 7) << 4);
      bf16x8 ah = *(const bf16x8*)(hb + byte);
      const int fi = ((nt * 16 + kb) * 64 + lane) * 8;
      bf16x8 bh = *(const bf16x8*)(WOhi + fi);
      bf16x8 bl_ = *(const bf16x8*)(WOlo + fi);
      acc = __builtin_amdgcn_mfma_f32_16x16x32_bf16(ah, bh, acc, 0, 0, 0);
      acc = __builtin_amdgcn_mfma_f32_16x16x32_bf16(ah, bl_, acc, 0, 0, 0);
    }
    const int rbase = bid * 16;
#pragma unroll
    for (int reg = 0; reg < 4; ++reg) {
      int row = rbase + kg * 4 + reg;
      out[(size_t)row * EE + nt * 16 + m] = fmaxf(acc[reg], 0.f);
    }
  }
#undef P1_TILE
#undef P1_SOFTMAX
}

extern "C" void kernel_launch(void* const* d_in, const int* in_sizes, int n_in,
                              void* d_out, int out_size, void* d_ws, size_t ws_size,
                              hipStream_t stream) {
  (void)in_sizes; (void)n_in; (void)out_size; (void)ws_size;
  const float* self_vecs  = (const float*)d_in[0];
  const float* neigh_vecs = (const float*)d_in[1];
  const float* W_heads    = (const float*)d_in[2];
  const float* a_self     = (const float*)d_in[3];
  const float* a_neigh    = (const float*)d_in[4];
  const float* W_out      = (const float*)d_in[5];
  float* out              = (float*)d_out;

  char* ws = (char*)d_ws;
  unsigned short* P1Whi = (unsigned short*)ws;                    // 4 KB
  unsigned short* P1Wlo = (unsigned short*)(ws + 4096);           // 4 KB
  unsigned short* WBhi  = (unsigned short*)(ws + 8192);           // 128 KB
  unsigned short* WBlo  = (unsigned short*)(ws + 8192 + 131072);
  unsigned short* WOhi  = (unsigned short*)(ws + 8192 + 262144);  // 64 KB
  unsigned short* WOlo  = (unsigned short*)(ws + 8192 + 262144 + 65536);

  prep_kernel<<<(2048 + 65536 + 32768) / 256, 256, 0, stream>>>(
      W_heads, a_self, a_neigh, W_out, P1Whi, P1Wlo, WBhi, WBlo, WOhi, WOlo);

  fused_kernel<<<BB / 4, 512, 0, stream>>>(
      self_vecs, neigh_vecs, P1Whi, P1Wlo, WBhi, WBlo, WOhi, WOlo, out);
}

// Round 14
// 71.909 us; speedup vs baseline: 1.1513x; 1.0043x over previous
//
#include <hip/hip_runtime.h>
#include <hip/hip_bf16.h>

#define BB 4096
#define NNB 20
#define GG 4
#define DIN 128
#define EE 64
#define HH 8

typedef short bf16x8 __attribute__((ext_vector_type(8)));
typedef float f32x4 __attribute__((ext_vector_type(4)));

__device__ __forceinline__ float lrelu_f(float x) { return x > 0.f ? x : 0.2f * x; }
__device__ __forceinline__ unsigned short f2bf(float f) {
  unsigned u = __float_as_uint(f);
  return (unsigned short)((u + 0x7fffu + ((u >> 16) & 1u)) >> 16);
}
__device__ __forceinline__ float bf2f(unsigned short s) {
  return __uint_as_float(((unsigned)s) << 16);
}

// ---------------- K0: prep (unchanged) ----------------
__global__ __launch_bounds__(256) void prep_kernel(
    const float* __restrict__ W_heads, const float* __restrict__ a_self,
    const float* __restrict__ a_neigh, const float* __restrict__ W_out,
    unsigned short* __restrict__ P1Whi, unsigned short* __restrict__ P1Wlo,
    unsigned short* __restrict__ WBhi, unsigned short* __restrict__ WBlo,
    unsigned short* __restrict__ WOhi, unsigned short* __restrict__ WOlo) {
  int id = blockIdx.x * 256 + threadIdx.x;
  if (id < 2048) {
    int j = id & 7, lane = (id >> 3) & 63, kb = id >> 9;
    int col = lane & 15, k = kb * 32 + (lane >> 4) * 8 + j;
    int h = col & 7;
    const float* a = (col < 8) ? a_neigh : a_self;
    const float* Wrow = W_heads + (h * DIN + k) * EE;
    float acc = 0.f;
    for (int e = 0; e < EE; ++e) acc = fmaf(Wrow[e], a[h * EE + e], acc);
    unsigned short hi = f2bf(acc);
    P1Whi[id] = hi;
    P1Wlo[id] = f2bf(acc - bf2f(hi));
  } else if (id < 2048 + 65536) {
    int rel = id - 2048;   // (((h*4+nt)*4+kb)*64 + l)*8 + j
    int j = rel & 7, l = (rel >> 3) & 63, kb = (rel >> 9) & 3, nt = (rel >> 11) & 3, h = rel >> 13;
    int d = kb * 32 + (l >> 4) * 8 + j;
    int e = nt * 16 + (l & 15);
    float w = W_heads[(h * DIN + d) * EE + e];
    unsigned short hi = f2bf(w);
    WBhi[rel] = hi;
    WBlo[rel] = f2bf(w - bf2f(hi));
  } else if (id < 2048 + 65536 + 32768) {
    int rel = id - 2048 - 65536;  // ((nt*16+kb)*64 + l)*8 + j
    int j = rel & 7, l = (rel >> 3) & 63, kb = (rel >> 9) & 15, nt = rel >> 13;
    int k = kb * 32 + (l >> 4) * 8 + j;
    int n = nt * 16 + (l & 15);
    float w = W_out[k * EE + n];
    unsigned short hi = f2bf(w);
    WOhi[rel] = hi;
    WOlo[rel] = f2bf(w - bf2f(hi));
  }
}

// ---------------- Fused kernel: 512 threads (8 waves), 4 b's = 16 bg rows ----------------
// LDS padded to 57,344 B so only 2 blocks/CU fit -> scheduler targets 4 waves/EU
// -> full 128-VGPR budget (R12's 3-block/85-reg target starved ILP at VGPR=52).
//   [0,32768):     agg bf16 [bg16][h8][d128], byte ^ ((bg&7)<<4)   (written in P3)
//   [32768,49152): P1-P3: att f32, word = n*128 + bg*8 + h (10,240 B used)
//                  B-C:   h bf16 [row16][k512], byte ^ ((row&7)<<4) (16,384 B)
//   [49152,57344): pad (occupancy control)
__global__ __launch_bounds__(512, 4) void fused_kernel(
    const float* __restrict__ self_vecs, const float* __restrict__ neigh_vecs,
    const unsigned short* __restrict__ P1Whi, const unsigned short* __restrict__ P1Wlo,
    const unsigned short* __restrict__ WBhi, const unsigned short* __restrict__ WBlo,
    const unsigned short* __restrict__ WOhi, const unsigned short* __restrict__ WOlo,
    float* __restrict__ out) {
  __shared__ char smem[57344];
  char* aggb = smem;
  float* attw = (float*)(smem + 32768);
  char* hb = smem + 32768;

  const int t = threadIdx.x;
  const int w = t >> 6, lane = t & 63;
  const int m = lane & 15, kg = lane >> 4;
  const int bid = blockIdx.x;

  // P1 weight frags in registers (B operand, constant across tiles)
  bf16x8 wfh[4], wfl[4];
#pragma unroll
  for (int kb = 0; kb < 4; ++kb) {
    wfh[kb] = *(const bf16x8*)(P1Whi + (kb * 64 + lane) * 8);
    wfl[kb] = *(const bf16x8*)(P1Wlo + (kb * 64 + lane) * 8);
  }

#define P1_TILE(rowp, cvec)                                                    \
  {                                                                            \
    _Pragma("unroll") for (int kb = 0; kb < 4; ++kb) {                         \
      float4 xa = *(const float4*)((rowp) + kb * 32 + kg * 8);                 \
      float4 xb = *(const float4*)((rowp) + kb * 32 + kg * 8 + 4);             \
      float xv[8] = {xa.x, xa.y, xa.z, xa.w, xb.x, xb.y, xb.z, xb.w};          \
      bf16x8 xh, xl;                                                           \
      _Pragma("unroll") for (int j = 0; j < 8; ++j) {                          \
        unsigned short hi = f2bf(xv[j]);                                       \
        xh[j] = (short)hi;                                                     \
        xl[j] = (short)f2bf(xv[j] - bf2f(hi));                                 \
      }                                                                        \
      cvec = __builtin_amdgcn_mfma_f32_16x16x32_bf16(xh, wfh[kb], cvec, 0, 0, 0); \
      cvec = __builtin_amdgcn_mfma_f32_16x16x32_bf16(xh, wfl[kb], cvec, 0, 0, 0); \
      cvec = __builtin_amdgcn_mfma_f32_16x16x32_bf16(xl, wfh[kb], cvec, 0, 0, 0); \
    }                                                                          \
  }

#define P1_SOFTMAX(tile, cvec)                                                 \
  if (m < 8) {                                                                 \
    float l[4], mx = -1e30f;                                                   \
    _Pragma("unroll") for (int gg = 0; gg < 4; ++gg) {                         \
      float v = lrelu_f(fs[gg] + (cvec)[gg]);                                  \
      l[gg] = v;                                                               \
      mx = fmaxf(mx, v);                                                       \
    }                                                                          \
    float s = 0.f;                                                             \
    _Pragma("unroll") for (int gg = 0; gg < 4; ++gg) {                         \
      l[gg] = __expf(l[gg] - mx);                                              \
      s += l[gg];                                                              \
    }                                                                          \
    float inv = 1.f / s;                                                       \
    _Pragma("unroll") for (int gg = 0; gg < 4; ++gg)                           \
      attw[(tile) * 128 + (kg * 4 + gg) * 8 + m] = l[gg] * inv;                \
  }

  // ======== P1a: self tile (redundant per wave, keeps fs in regs) ========
  f32x4 fs;
  {
    f32x4 c20 = {0.f, 0.f, 0.f, 0.f};
    const float* srow = self_vecs + ((size_t)bid * 16 + m) * DIN;
    P1_TILE(srow, c20)
#pragma unroll
    for (int reg = 0; reg < 4; ++reg) fs[reg] = __shfl_xor(c20[reg], 8);
  }

  // ======== P1b: n-tiles (straight-line: w, w+8, guarded w+16) ========
  const int bl_m = m >> 2, g_m = m & 3;
  const float* base_n =
      neigh_vecs + ((size_t)(bid * 4 + bl_m) * NNB * GG + g_m) * DIN;
  {
    f32x4 cA = {0.f, 0.f, 0.f, 0.f}, cB = {0.f, 0.f, 0.f, 0.f};
    const float* rpA = base_n + (size_t)w * (GG * DIN);
    const float* rpB = base_n + (size_t)(w + 8) * (GG * DIN);
    P1_TILE(rpA, cA)
    P1_TILE(rpB, cB)
    if (w < 4) {
      f32x4 cC = {0.f, 0.f, 0.f, 0.f};
      const float* rpC = base_n + (size_t)(w + 16) * (GG * DIN);
      P1_TILE(rpC, cC)
      P1_SOFTMAX(w + 16, cC)
    }
    P1_SOFTMAX(w, cA)
    P1_SOFTMAX(w + 8, cB)
  }
  __syncthreads();   // att complete

  // ======== P3: agg[bg][h][d] = sum_n att*x ; wave w -> bg {2w, 2w+1} ========
#pragma unroll
  for (int i = 0; i < 2; ++i) {
    const int bg = 2 * w + i;
    const int bl = bg >> 2, g = bg & 3;
    const float* nbw = neigh_vecs + ((size_t)(bid * 4 + bl) * NNB * GG + g) * DIN;
    float acc[8][2];
#pragma unroll
    for (int h = 0; h < 8; ++h) { acc[h][0] = 0.f; acc[h][1] = 0.f; }
#pragma unroll
    for (int n = 0; n < NNB; ++n) {
      float2 x2 = *(const float2*)&nbw[(size_t)n * GG * DIN + 2 * lane];
      f32x4 a0 = *(const f32x4*)&attw[n * 128 + bg * 8];      // uniform -> broadcast
      f32x4 a1 = *(const f32x4*)&attw[n * 128 + bg * 8 + 4];
#pragma unroll
      for (int h = 0; h < 4; ++h) {
        acc[h][0] = fmaf(a0[h], x2.x, acc[h][0]);
        acc[h][1] = fmaf(a0[h], x2.y, acc[h][1]);
        acc[h + 4][0] = fmaf(a1[h], x2.x, acc[h + 4][0]);
        acc[h + 4][1] = fmaf(a1[h], x2.y, acc[h + 4][1]);
      }
    }
    const int swz = (bg & 7) << 4;
#pragma unroll
    for (int h = 0; h < 8; ++h) {
      unsigned pack = (unsigned)f2bf(acc[h][0]) | ((unsigned)f2bf(acc[h][1]) << 16);
      *(unsigned*)(aggb + ((bg * 2048 + h * 256 + 4 * lane) ^ swz)) = pack;
    }
  }
  __syncthreads();   // agg complete; att dead -> hb reuse

  // ======== phase B: head transform, wave w -> hh = w; h stored bf16 ========
  {
    const int hh = w;
    const int aswz = (m & 7) << 4;
    bf16x8 a[4];
#pragma unroll
    for (int kb = 0; kb < 4; ++kb)
      a[kb] = *(const bf16x8*)(aggb + ((m * 2048 + hh * 256 + kb * 64 + kg * 16) ^ aswz));
#pragma unroll
    for (int nt = 0; nt < 4; ++nt) {
      f32x4 c = {0.f, 0.f, 0.f, 0.f};
#pragma unroll
      for (int kb = 0; kb < 4; ++kb) {
        const int fi = (((hh * 4 + nt) * 4 + kb) * 64 + lane) * 8;
        bf16x8 bh = *(const bf16x8*)(WBhi + fi);
        bf16x8 bl_ = *(const bf16x8*)(WBlo + fi);
        c = __builtin_amdgcn_mfma_f32_16x16x32_bf16(a[kb], bh, c, 0, 0, 0);
        c = __builtin_amdgcn_mfma_f32_16x16x32_bf16(a[kb], bl_, c, 0, 0, 0);
      }
      const int k = hh * 64 + nt * 16 + m;
#pragma unroll
      for (int reg = 0; reg < 4; ++reg) {
        int row = kg * 4 + reg;
        int byte = (row * 1024 + k * 2) ^ ((row & 7) << 4);
        *(unsigned short*)(hb + byte) = f2bf(lrelu_f(c[reg]));
      }
    }
  }
  __syncthreads();

  // ======== phase C: final FC, waves 0..3, nt = w ========
  if (w < 4) {
    const int nt = w;
    f32x4 acc = {0.f, 0.f, 0.f, 0.f};
    for (int kb = 0; kb < 16; ++kb) {
      int byte = (m * 1024 + (kb * 32 + kg * 8) * 2) ^ ((m & 7) << 4);
      bf16x8 ah = *(const bf16x8*)(hb + byte);
      const int fi = ((nt * 16 + kb) * 64 + lane) * 8;
      bf16x8 bh = *(const bf16x8*)(WOhi + fi);
      bf16x8 bl_ = *(const bf16x8*)(WOlo + fi);
      acc = __builtin_amdgcn_mfma_f32_16x16x32_bf16(ah, bh, acc, 0, 0, 0);
      acc = __builtin_amdgcn_mfma_f32_16x16x32_bf16(ah, bl_, acc, 0, 0, 0);
    }
    const int rbase = bid * 16;
#pragma unroll
    for (int reg = 0; reg < 4; ++reg) {
      int row = rbase + kg * 4 + reg;
      out[(size_t)row * EE + nt * 16 + m] = fmaxf(acc[reg], 0.f);
    }
  }
#undef P1_TILE
#undef P1_SOFTMAX
}

extern "C" void kernel_launch(void* const* d_in, const int* in_sizes, int n_in,
                              void* d_out, int out_size, void* d_ws, size_t ws_size,
                              hipStream_t stream) {
  (void)in_sizes; (void)n_in; (void)out_size; (void)ws_size;
  const float* self_vecs  = (const float*)d_in[0];
  const float* neigh_vecs = (const float*)d_in[1];
  const float* W_heads    = (const float*)d_in[2];
  const float* a_self     = (const float*)d_in[3];
  const float* a_neigh    = (const float*)d_in[4];
  const float* W_out      = (const float*)d_in[5];
  float* out              = (float*)d_out;

  char* ws = (char*)d_ws;
  unsigned short* P1Whi = (unsigned short*)ws;                    // 4 KB
  unsigned short* P1Wlo = (unsigned short*)(ws + 4096);           // 4 KB
  unsigned short* WBhi  = (unsigned short*)(ws + 8192);           // 128 KB
  unsigned short* WBlo  = (unsigned short*)(ws + 8192 + 131072);
  unsigned short* WOhi  = (unsigned short*)(ws + 8192 + 262144);  // 64 KB
  unsigned short* WOlo  = (unsigned short*)(ws + 8192 + 262144 + 65536);

  prep_kernel<<<(2048 + 65536 + 32768) / 256, 256, 0, stream>>>(
      W_heads, a_self, a_neigh, W_out, P1Whi, P1Wlo, WBhi, WBlo, WOhi, WOlo);

  fused_kernel<<<BB / 4, 512, 0, stream>>>(
      self_vecs, neigh_vecs, P1Whi, P1Wlo, WBhi, WBlo, WOhi, WOlo, out);
}

// Round 15
// 71.373 us; speedup vs baseline: 1.1600x; 1.0075x over previous
//
#include <hip/hip_runtime.h>
#include <hip/hip_bf16.h>

#define BB 4096
#define NNB 20
#define GG 4
#define DIN 128
#define EE 64
#define HH 8

typedef short bf16x8 __attribute__((ext_vector_type(8)));
typedef float f32x4 __attribute__((ext_vector_type(4)));

__device__ __forceinline__ float lrelu_f(float x) { return x > 0.f ? x : 0.2f * x; }
__device__ __forceinline__ unsigned short f2bf(float f) {
  unsigned u = __float_as_uint(f);
  return (unsigned short)((u + 0x7fffu + ((u >> 16) & 1u)) >> 16);
}
__device__ __forceinline__ float bf2f(unsigned short s) {
  return __uint_as_float(((unsigned)s) << 16);
}

// ---------------- K0: prep (unchanged) ----------------
__global__ __launch_bounds__(256) void prep_kernel(
    const float* __restrict__ W_heads, const float* __restrict__ a_self,
    const float* __restrict__ a_neigh, const float* __restrict__ W_out,
    unsigned short* __restrict__ P1Whi, unsigned short* __restrict__ P1Wlo,
    unsigned short* __restrict__ WBhi, unsigned short* __restrict__ WBlo,
    unsigned short* __restrict__ WOhi, unsigned short* __restrict__ WOlo) {
  int id = blockIdx.x * 256 + threadIdx.x;
  if (id < 2048) {
    int j = id & 7, lane = (id >> 3) & 63, kb = id >> 9;
    int col = lane & 15, k = kb * 32 + (lane >> 4) * 8 + j;
    int h = col & 7;
    const float* a = (col < 8) ? a_neigh : a_self;
    const float* Wrow = W_heads + (h * DIN + k) * EE;
    float acc = 0.f;
    for (int e = 0; e < EE; ++e) acc = fmaf(Wrow[e], a[h * EE + e], acc);
    unsigned short hi = f2bf(acc);
    P1Whi[id] = hi;
    P1Wlo[id] = f2bf(acc - bf2f(hi));
  } else if (id < 2048 + 65536) {
    int rel = id - 2048;   // (((h*4+nt)*4+kb)*64 + l)*8 + j
    int j = rel & 7, l = (rel >> 3) & 63, kb = (rel >> 9) & 3, nt = (rel >> 11) & 3, h = rel >> 13;
    int d = kb * 32 + (l >> 4) * 8 + j;
    int e = nt * 16 + (l & 15);
    float w = W_heads[(h * DIN + d) * EE + e];
    unsigned short hi = f2bf(w);
    WBhi[rel] = hi;
    WBlo[rel] = f2bf(w - bf2f(hi));
  } else if (id < 2048 + 65536 + 32768) {
    int rel = id - 2048 - 65536;  // ((nt*16+kb)*64 + l)*8 + j
    int j = rel & 7, l = (rel >> 3) & 63, kb = (rel >> 9) & 15, nt = rel >> 13;
    int k = kb * 32 + (l >> 4) * 8 + j;
    int n = nt * 16 + (l & 15);
    float w = W_out[k * EE + n];
    unsigned short hi = f2bf(w);
    WOhi[rel] = hi;
    WOlo[rel] = f2bf(w - bf2f(hi));
  }
}

// ---------------- Fused kernel: 512 threads (8 waves), 4 b's = 16 bg rows ----------------
// LDS 57,344 B (2 blocks/CU):
//   [0,32768):     P1: wf staging [0,8192) (hi,lo). P3+: agg bf16 [bg16][h8][d128],
//                  byte ^ ((bg&7)<<4).
//   [32768,49152): P1-P3: att f32, word = n*128 + bg*8 + h. B-C: h bf16
//                  [row16][k512], byte ^ ((row&7)<<4).
//   [49152,57344): pad (occupancy control)
// P1 x-loads are explicitly hoisted into float4 X[8] batches so ~24 global
// loads are in flight per wave (R12-14 were latency-bound at ~4 in flight).
__global__ __launch_bounds__(512, 4) void fused_kernel(
    const float* __restrict__ self_vecs, const float* __restrict__ neigh_vecs,
    const unsigned short* __restrict__ P1Whi, const unsigned short* __restrict__ P1Wlo,
    const unsigned short* __restrict__ WBhi, const unsigned short* __restrict__ WBlo,
    const unsigned short* __restrict__ WOhi, const unsigned short* __restrict__ WOlo,
    float* __restrict__ out) {
  __shared__ char smem[57344];
  char* aggb = smem;
  float* attw = (float*)(smem + 32768);
  char* hb = smem + 32768;

  const int t = threadIdx.x;
  const int w = t >> 6, lane = t & 63;
  const int m = lane & 15, kg = lane >> 4;
  const int bid = blockIdx.x;

  // ---- load one tile's 8 float4 (static indexing -> registers) ----
#define LOAD_X(X, ptr)                                                         \
  {                                                                            \
    const float4* p_ = (const float4*)(ptr);                                   \
    _Pragma("unroll") for (int q = 0; q < 4; ++q) {                            \
      X[2 * q]     = p_[q * 8 + kg * 2];                                       \
      X[2 * q + 1] = p_[q * 8 + kg * 2 + 1];                                   \
    }                                                                          \
  }

  // ---- convert + 12 MFMA for one tile; wf read from LDS [0,8192) ----
#define PROC_TILE(X, cvec)                                                     \
  {                                                                            \
    _Pragma("unroll") for (int kb = 0; kb < 4; ++kb) {                         \
      float xv[8] = {X[2 * kb].x,     X[2 * kb].y,     X[2 * kb].z,            \
                     X[2 * kb].w,     X[2 * kb + 1].x, X[2 * kb + 1].y,        \
                     X[2 * kb + 1].z, X[2 * kb + 1].w};                        \
      bf16x8 xh, xl;                                                           \
      _Pragma("unroll") for (int j = 0; j < 8; ++j) {                          \
        unsigned short hi = f2bf(xv[j]);                                       \
        xh[j] = (short)hi;                                                     \
        xl[j] = (short)f2bf(xv[j] - bf2f(hi));                                 \
      }                                                                        \
      bf16x8 wh = *(const bf16x8*)(smem + kb * 1024 + lane * 16);              \
      bf16x8 wl = *(const bf16x8*)(smem + 4096 + kb * 1024 + lane * 16);       \
      cvec = __builtin_amdgcn_mfma_f32_16x16x32_bf16(xh, wh, cvec, 0, 0, 0);   \
      cvec = __builtin_amdgcn_mfma_f32_16x16x32_bf16(xh, wl, cvec, 0, 0, 0);   \
      cvec = __builtin_amdgcn_mfma_f32_16x16x32_bf16(xl, wh, cvec, 0, 0, 0);   \
    }                                                                          \
  }

#define P1_SOFTMAX(tile, cvec)                                                 \
  if (m < 8) {                                                                 \
    float l[4], mx = -1e30f;                                                   \
    _Pragma("unroll") for (int gg = 0; gg < 4; ++gg) {                         \
      float v = lrelu_f(fs[gg] + (cvec)[gg]);                                  \
      l[gg] = v;                                                               \
      mx = fmaxf(mx, v);                                                       \
    }                                                                          \
    float s = 0.f;                                                             \
    _Pragma("unroll") for (int gg = 0; gg < 4; ++gg) {                         \
      l[gg] = __expf(l[gg] - mx);                                              \
      s += l[gg];                                                              \
    }                                                                          \
    float inv = 1.f / s;                                                       \
    _Pragma("unroll") for (int gg = 0; gg < 4; ++gg)                           \
      attw[(tile) * 128 + (kg * 4 + gg) * 8 + m] = l[gg] * inv;                \
  }

  const int bl_m = m >> 2, g_m = m & 3;
  const float* base_n =
      neigh_vecs + ((size_t)(bid * 4 + bl_m) * NNB * GG + g_m) * DIN;

  // ---- issue self + tile-A loads (in flight across the staging barrier) ----
  float4 XS[8], XA[8], XB[8], XC[8];
  LOAD_X(XS, self_vecs + ((size_t)bid * 16 + m) * DIN)
  LOAD_X(XA, base_n + (size_t)w * (GG * DIN))

  // ---- stage P1 weights into LDS [0,8192) ----
  {
    const float4* src = (t < 256) ? (const float4*)P1Whi : (const float4*)P1Wlo;
    ((float4*)smem)[t] = src[t & 255];
  }
  __syncthreads();

  // ======== P1a: self tile (redundant per wave) ========
  f32x4 fs;
  {
    f32x4 c20 = {0.f, 0.f, 0.f, 0.f};
    PROC_TILE(XS, c20)
#pragma unroll
    for (int reg = 0; reg < 4; ++reg) fs[reg] = __shfl_xor(c20[reg], 8);
  }
  LOAD_X(XB, base_n + (size_t)(w + 8) * (GG * DIN))

  // ======== P1b: n-tiles ========
  f32x4 cA = {0.f, 0.f, 0.f, 0.f}, cB = {0.f, 0.f, 0.f, 0.f};
  PROC_TILE(XA, cA)
  if (w < 4) LOAD_X(XC, base_n + (size_t)(w + 16) * (GG * DIN))
  PROC_TILE(XB, cB)
  if (w < 4) {
    f32x4 cC = {0.f, 0.f, 0.f, 0.f};
    PROC_TILE(XC, cC)
    P1_SOFTMAX(w + 16, cC)
  }
  P1_SOFTMAX(w, cA)
  P1_SOFTMAX(w + 8, cB)
  __syncthreads();   // att complete; wf staging dead -> agg region free

  // ======== P3: agg[bg][h][d] = sum_n att*x ; wave w -> bg {2w, 2w+1} ========
#pragma unroll
  for (int i = 0; i < 2; ++i) {
    const int bg = 2 * w + i;
    const int bl = bg >> 2, g = bg & 3;
    const float* nbw = neigh_vecs + ((size_t)(bid * 4 + bl) * NNB * GG + g) * DIN;
    float acc[8][2];
#pragma unroll
    for (int h = 0; h < 8; ++h) { acc[h][0] = 0.f; acc[h][1] = 0.f; }
#pragma unroll
    for (int n = 0; n < NNB; ++n) {
      float2 x2 = *(const float2*)&nbw[(size_t)n * GG * DIN + 2 * lane];
      f32x4 a0 = *(const f32x4*)&attw[n * 128 + bg * 8];      // uniform -> broadcast
      f32x4 a1 = *(const f32x4*)&attw[n * 128 + bg * 8 + 4];
#pragma unroll
      for (int h = 0; h < 4; ++h) {
        acc[h][0] = fmaf(a0[h], x2.x, acc[h][0]);
        acc[h][1] = fmaf(a0[h], x2.y, acc[h][1]);
        acc[h + 4][0] = fmaf(a1[h], x2.x, acc[h + 4][0]);
        acc[h + 4][1] = fmaf(a1[h], x2.y, acc[h + 4][1]);
      }
    }
    const int swz = (bg & 7) << 4;
#pragma unroll
    for (int h = 0; h < 8; ++h) {
      unsigned pack = (unsigned)f2bf(acc[h][0]) | ((unsigned)f2bf(acc[h][1]) << 16);
      *(unsigned*)(aggb + ((bg * 2048 + h * 256 + 4 * lane) ^ swz)) = pack;
    }
  }
  __syncthreads();   // agg complete; att dead -> hb reuse

  // ======== phase B: head transform, wave w -> hh = w; h stored bf16 ========
  {
    const int hh = w;
    const int aswz = (m & 7) << 4;
    bf16x8 a[4];
#pragma unroll
    for (int kb = 0; kb < 4; ++kb)
      a[kb] = *(const bf16x8*)(aggb + ((m * 2048 + hh * 256 + kb * 64 + kg * 16) ^ aswz));
#pragma unroll
    for (int nt = 0; nt < 4; ++nt) {
      f32x4 c = {0.f, 0.f, 0.f, 0.f};
#pragma unroll
      for (int kb = 0; kb < 4; ++kb) {
        const int fi = (((hh * 4 + nt) * 4 + kb) * 64 + lane) * 8;
        bf16x8 bh = *(const bf16x8*)(WBhi + fi);
        bf16x8 bl_ = *(const bf16x8*)(WBlo + fi);
        c = __builtin_amdgcn_mfma_f32_16x16x32_bf16(a[kb], bh, c, 0, 0, 0);
        c = __builtin_amdgcn_mfma_f32_16x16x32_bf16(a[kb], bl_, c, 0, 0, 0);
      }
      const int k = hh * 64 + nt * 16 + m;
#pragma unroll
      for (int reg = 0; reg < 4; ++reg) {
        int row = kg * 4 + reg;
        int byte = (row * 1024 + k * 2) ^ ((row & 7) << 4);
        *(unsigned short*)(hb + byte) = f2bf(lrelu_f(c[reg]));
      }
    }
  }
  __syncthreads();

  // ======== phase C: final FC, waves 0..3, nt = w ========
  if (w < 4) {
    const int nt = w;
    f32x4 acc = {0.f, 0.f, 0.f, 0.f};
    for (int kb = 0; kb < 16; ++kb) {
      int byte = (m * 1024 + (kb * 32 + kg * 8) * 2) ^ ((m & 7) << 4);
      bf16x8 ah = *(const bf16x8*)(hb + byte);
      const int fi = ((nt * 16 + kb) * 64 + lane) * 8;
      bf16x8 bh = *(const bf16x8*)(WOhi + fi);
      bf16x8 bl_ = *(const bf16x8*)(WOlo + fi);
      acc = __builtin_amdgcn_mfma_f32_16x16x32_bf16(ah, bh, acc, 0, 0, 0);
      acc = __builtin_amdgcn_mfma_f32_16x16x32_bf16(ah, bl_, acc, 0, 0, 0);
    }
    const int rbase = bid * 16;
#pragma unroll
    for (int reg = 0; reg < 4; ++reg) {
      int row = rbase + kg * 4 + reg;
      out[(size_t)row * EE + nt * 16 + m] = fmaxf(acc[reg], 0.f);
    }
  }
#undef LOAD_X
#undef PROC_TILE
#undef P1_SOFTMAX
}

extern "C" void kernel_launch(void* const* d_in, const int* in_sizes, int n_in,
                              void* d_out, int out_size, void* d_ws, size_t ws_size,
                              hipStream_t stream) {
  (void)in_sizes; (void)n_in; (void)out_size; (void)ws_size;
  const float* self_vecs  = (const float*)d_in[0];
  const float* neigh_vecs = (const float*)d_in[1];
  const float* W_heads    = (const float*)d_in[2];
  const float* a_self     = (const float*)d_in[3];
  const float* a_neigh    = (const float*)d_in[4];
  const float* W_out      = (const float*)d_in[5];
  float* out              = (float*)d_out;

  char* ws = (char*)d_ws;
  unsigned short* P1Whi = (unsigned short*)ws;                    // 4 KB
  unsigned short* P1Wlo = (unsigned short*)(ws + 4096);           // 4 KB
  unsigned short* WBhi  = (unsigned short*)(ws + 8192);           // 128 KB
  unsigned short* WBlo  = (unsigned short*)(ws + 8192 + 131072);
  unsigned short* WOhi  = (unsigned short*)(ws + 8192 + 262144);  // 64 KB
  unsigned short* WOlo  = (unsigned short*)(ws + 8192 + 262144 + 65536);

  prep_kernel<<<(2048 + 65536 + 32768) / 256, 256, 0, stream>>>(
      W_heads, a_self, a_neigh, W_out, P1Whi, P1Wlo, WBhi, WBlo, WOhi, WOlo);

  fused_kernel<<<BB / 4, 512, 0, stream>>>(
      self_vecs, neigh_vecs, P1Whi, P1Wlo, WBhi, WBlo, WOhi, WOlo, out);
}

// Round 16
// 68.066 us; speedup vs baseline: 1.2163x; 1.0486x over previous
//
#include <hip/hip_runtime.h>
#include <hip/hip_bf16.h>

#define BB 4096
#define NNB 20
#define GG 4
#define DIN 128
#define EE 64
#define HH 8

typedef short bf16x8 __attribute__((ext_vector_type(8)));
typedef float f32x4 __attribute__((ext_vector_type(4)));

__device__ __forceinline__ float lrelu_f(float x) { return x > 0.f ? x : 0.2f * x; }
__device__ __forceinline__ unsigned short f2bf(float f) {
  unsigned u = __float_as_uint(f);
  return (unsigned short)((u + 0x7fffu + ((u >> 16) & 1u)) >> 16);
}
__device__ __forceinline__ float bf2f(unsigned short s) {
  return __uint_as_float(((unsigned)s) << 16);
}

// ---------------- K0: prep (unchanged) ----------------
__global__ __launch_bounds__(256) void prep_kernel(
    const float* __restrict__ W_heads, const float* __restrict__ a_self,
    const float* __restrict__ a_neigh, const float* __restrict__ W_out,
    unsigned short* __restrict__ P1Whi, unsigned short* __restrict__ P1Wlo,
    unsigned short* __restrict__ WBhi, unsigned short* __restrict__ WBlo,
    unsigned short* __restrict__ WOhi, unsigned short* __restrict__ WOlo) {
  int id = blockIdx.x * 256 + threadIdx.x;
  if (id < 2048) {
    int j = id & 7, lane = (id >> 3) & 63, kb = id >> 9;
    int col = lane & 15, k = kb * 32 + (lane >> 4) * 8 + j;
    int h = col & 7;
    const float* a = (col < 8) ? a_neigh : a_self;
    const float* Wrow = W_heads + (h * DIN + k) * EE;
    float acc = 0.f;
    for (int e = 0; e < EE; ++e) acc = fmaf(Wrow[e], a[h * EE + e], acc);
    unsigned short hi = f2bf(acc);
    P1Whi[id] = hi;
    P1Wlo[id] = f2bf(acc - bf2f(hi));
  } else if (id < 2048 + 65536) {
    int rel = id - 2048;   // (((h*4+nt)*4+kb)*64 + l)*8 + j
    int j = rel & 7, l = (rel >> 3) & 63, kb = (rel >> 9) & 3, nt = (rel >> 11) & 3, h = rel >> 13;
    int d = kb * 32 + (l >> 4) * 8 + j;
    int e = nt * 16 + (l & 15);
    float w = W_heads[(h * DIN + d) * EE + e];
    unsigned short hi = f2bf(w);
    WBhi[rel] = hi;
    WBlo[rel] = f2bf(w - bf2f(hi));
  } else if (id < 2048 + 65536 + 32768) {
    int rel = id - 2048 - 65536;  // ((nt*16+kb)*64 + l)*8 + j
    int j = rel & 7, l = (rel >> 3) & 63, kb = (rel >> 9) & 15, nt = rel >> 13;
    int k = kb * 32 + (l >> 4) * 8 + j;
    int n = nt * 16 + (l & 15);
    float w = W_out[k * EE + n];
    unsigned short hi = f2bf(w);
    WOhi[rel] = hi;
    WOlo[rel] = f2bf(w - bf2f(hi));
  }
}

// ---------------- Fused kernel: 512 threads (8 waves), 4 b's = 16 bg rows ----------------
// LDS 57,344 B (2 blocks/CU):
//   [0,32768):     P1: wf staging [0,8192). P3+: agg bf16 [bg16][h8][d128],
//                  byte ^ ((bg&7)<<4).
//   [32768,49152): P1-P3: att f32, word = n*128 + bg*8 + h. B-C: h bf16
//                  [row16][k512], byte ^ ((row&7)<<4).
//   [49152,57344): pad (occupancy control)
// R16: P1 uses A=bf16(x) hi-only (B stays hi/lo split) -> ~45% less P1 VALU;
//      P3 dual-bg float4 (lane<32 -> g0 row, lane>=32 -> g1 row) -> half the loads.
__global__ __launch_bounds__(512, 4) void fused_kernel(
    const float* __restrict__ self_vecs, const float* __restrict__ neigh_vecs,
    const unsigned short* __restrict__ P1Whi, const unsigned short* __restrict__ P1Wlo,
    const unsigned short* __restrict__ WBhi, const unsigned short* __restrict__ WBlo,
    const unsigned short* __restrict__ WOhi, const unsigned short* __restrict__ WOlo,
    float* __restrict__ out) {
  __shared__ char smem[57344];
  char* aggb = smem;
  float* attw = (float*)(smem + 32768);
  char* hb = smem + 32768;

  const int t = threadIdx.x;
  const int w = t >> 6, lane = t & 63;
  const int m = lane & 15, kg = lane >> 4;
  const int bid = blockIdx.x;

#define LOAD_X(X, ptr)                                                         \
  {                                                                            \
    const float4* p_ = (const float4*)(ptr);                                   \
    _Pragma("unroll") for (int q = 0; q < 4; ++q) {                            \
      X[2 * q]     = p_[q * 8 + kg * 2];                                       \
      X[2 * q + 1] = p_[q * 8 + kg * 2 + 1];                                   \
    }                                                                          \
  }

  // ---- convert (hi only) + 8 MFMA for one tile; wf read from LDS [0,8192) ----
#define PROC_TILE(X, cvec)                                                     \
  {                                                                            \
    _Pragma("unroll") for (int kb = 0; kb < 4; ++kb) {                         \
      float xv[8] = {X[2 * kb].x,     X[2 * kb].y,     X[2 * kb].z,            \
                     X[2 * kb].w,     X[2 * kb + 1].x, X[2 * kb + 1].y,        \
                     X[2 * kb + 1].z, X[2 * kb + 1].w};                        \
      bf16x8 xh;                                                               \
      _Pragma("unroll") for (int j = 0; j < 8; ++j) xh[j] = (short)f2bf(xv[j]); \
      bf16x8 wh = *(const bf16x8*)(smem + kb * 1024 + lane * 16);              \
      bf16x8 wl = *(const bf16x8*)(smem + 4096 + kb * 1024 + lane * 16);       \
      cvec = __builtin_amdgcn_mfma_f32_16x16x32_bf16(xh, wh, cvec, 0, 0, 0);   \
      cvec = __builtin_amdgcn_mfma_f32_16x16x32_bf16(xh, wl, cvec, 0, 0, 0);   \
    }                                                                          \
  }

#define P1_SOFTMAX(tile, cvec)                                                 \
  if (m < 8) {                                                                 \
    float l[4], mx = -1e30f;                                                   \
    _Pragma("unroll") for (int gg = 0; gg < 4; ++gg) {                         \
      float v = lrelu_f(fs[gg] + (cvec)[gg]);                                  \
      l[gg] = v;                                                               \
      mx = fmaxf(mx, v);                                                       \
    }                                                                          \
    float s = 0.f;                                                             \
    _Pragma("unroll") for (int gg = 0; gg < 4; ++gg) {                         \
      l[gg] = __expf(l[gg] - mx);                                              \
      s += l[gg];                                                              \
    }                                                                          \
    float inv = 1.f / s;                                                       \
    _Pragma("unroll") for (int gg = 0; gg < 4; ++gg)                           \
      attw[(tile) * 128 + (kg * 4 + gg) * 8 + m] = l[gg] * inv;                \
  }

  const int bl_m = m >> 2, g_m = m & 3;
  const float* base_n =
      neigh_vecs + ((size_t)(bid * 4 + bl_m) * NNB * GG + g_m) * DIN;

  // ---- issue self + tile-A loads (in flight across the staging barrier) ----
  float4 XS[8], XA[8], XB[8], XC[8];
  LOAD_X(XS, self_vecs + ((size_t)bid * 16 + m) * DIN)
  LOAD_X(XA, base_n + (size_t)w * (GG * DIN))

  // ---- stage P1 weights into LDS [0,8192) ----
  {
    const float4* src = (t < 256) ? (const float4*)P1Whi : (const float4*)P1Wlo;
    ((float4*)smem)[t] = src[t & 255];
  }
  __syncthreads();

  // ======== P1a: self tile (redundant per wave) ========
  f32x4 fs;
  {
    f32x4 c20 = {0.f, 0.f, 0.f, 0.f};
    PROC_TILE(XS, c20)
#pragma unroll
    for (int reg = 0; reg < 4; ++reg) fs[reg] = __shfl_xor(c20[reg], 8);
  }
  LOAD_X(XB, base_n + (size_t)(w + 8) * (GG * DIN))

  // ======== P1b: n-tiles ========
  f32x4 cA = {0.f, 0.f, 0.f, 0.f}, cB = {0.f, 0.f, 0.f, 0.f};
  PROC_TILE(XA, cA)
  if (w < 4) LOAD_X(XC, base_n + (size_t)(w + 16) * (GG * DIN))
  PROC_TILE(XB, cB)
  if (w < 4) {
    f32x4 cC = {0.f, 0.f, 0.f, 0.f};
    PROC_TILE(XC, cC)
    P1_SOFTMAX(w + 16, cC)
  }
  P1_SOFTMAX(w, cA)
  P1_SOFTMAX(w + 8, cB)
  __syncthreads();   // att complete; wf staging dead -> agg region free

  // ======== P3: dual-bg. Lane covers bg = 2w + (lane>=32), d = 4*(lane&31)..+4 ========
  {
    const int ih = lane >> 5;              // 0 -> g0 row, 1 -> g1 row
    const int bg = 2 * w + ih;
    const int bl = w >> 1;
    const int g0 = (2 * w) & 3;
    const float* nb2 =
        neigh_vecs + ((size_t)(bid * 4 + bl) * NNB * GG + g0) * DIN;
    const int dl = 4 * (lane & 31);        // d base for this lane
    float acc[8][4];
#pragma unroll
    for (int h = 0; h < 8; ++h)
#pragma unroll
      for (int d = 0; d < 4; ++d) acc[h][d] = 0.f;
#pragma unroll
    for (int n = 0; n < NNB; ++n) {
      float4 x4 = *(const float4*)&nb2[(size_t)n * GG * DIN + 4 * lane];
      f32x4 a0 = *(const f32x4*)&attw[n * 128 + bg * 8];     // 2-way broadcast
      f32x4 a1 = *(const f32x4*)&attw[n * 128 + bg * 8 + 4];
#pragma unroll
      for (int h = 0; h < 4; ++h) {
        acc[h][0] = fmaf(a0[h], x4.x, acc[h][0]);
        acc[h][1] = fmaf(a0[h], x4.y, acc[h][1]);
        acc[h][2] = fmaf(a0[h], x4.z, acc[h][2]);
        acc[h][3] = fmaf(a0[h], x4.w, acc[h][3]);
        acc[h + 4][0] = fmaf(a1[h], x4.x, acc[h + 4][0]);
        acc[h + 4][1] = fmaf(a1[h], x4.y, acc[h + 4][1]);
        acc[h + 4][2] = fmaf(a1[h], x4.z, acc[h + 4][2]);
        acc[h + 4][3] = fmaf(a1[h], x4.w, acc[h + 4][3]);
      }
    }
    const int swz = (bg & 7) << 4;
#pragma unroll
    for (int h = 0; h < 8; ++h) {
      uint2 pk;
      pk.x = (unsigned)f2bf(acc[h][0]) | ((unsigned)f2bf(acc[h][1]) << 16);
      pk.y = (unsigned)f2bf(acc[h][2]) | ((unsigned)f2bf(acc[h][3]) << 16);
      *(uint2*)(aggb + ((bg * 2048 + h * 256 + 2 * dl) ^ swz)) = pk;
    }
  }
  __syncthreads();   // agg complete; att dead -> hb reuse

  // ======== phase B: head transform, wave w -> hh = w; h stored bf16 ========
  {
    const int hh = w;
    const int aswz = (m & 7) << 4;
    bf16x8 a[4];
#pragma unroll
    for (int kb = 0; kb < 4; ++kb)
      a[kb] = *(const bf16x8*)(aggb + ((m * 2048 + hh * 256 + kb * 64 + kg * 16) ^ aswz));
#pragma unroll
    for (int nt = 0; nt < 4; ++nt) {
      f32x4 c = {0.f, 0.f, 0.f, 0.f};
#pragma unroll
      for (int kb = 0; kb < 4; ++kb) {
        const int fi = (((hh * 4 + nt) * 4 + kb) * 64 + lane) * 8;
        bf16x8 bh = *(const bf16x8*)(WBhi + fi);
        bf16x8 bl_ = *(const bf16x8*)(WBlo + fi);
        c = __builtin_amdgcn_mfma_f32_16x16x32_bf16(a[kb], bh, c, 0, 0, 0);
        c = __builtin_amdgcn_mfma_f32_16x16x32_bf16(a[kb], bl_, c, 0, 0, 0);
      }
      const int k = hh * 64 + nt * 16 + m;
#pragma unroll
      for (int reg = 0; reg < 4; ++reg) {
        int row = kg * 4 + reg;
        int byte = (row * 1024 + k * 2) ^ ((row & 7) << 4);
        *(unsigned short*)(hb + byte) = f2bf(lrelu_f(c[reg]));
      }
    }
  }
  __syncthreads();

  // ======== phase C: final FC, waves 0..3, nt = w ========
  if (w < 4) {
    const int nt = w;
    f32x4 acc = {0.f, 0.f, 0.f, 0.f};
    for (int kb = 0; kb < 16; ++kb) {
      int byte = (m * 1024 + (kb * 32 + kg * 8) * 2) ^ ((m & 7) << 4);
      bf16x8 ah = *(const bf16x8*)(hb + byte);
      const int fi = ((nt * 16 + kb) * 64 + lane) * 8;
      bf16x8 bh = *(const bf16x8*)(WOhi + fi);
      bf16x8 bl_ = *(const bf16x8*)(WOlo + fi);
      acc = __builtin_amdgcn_mfma_f32_16x16x32_bf16(ah, bh, acc, 0, 0, 0);
      acc = __builtin_amdgcn_mfma_f32_16x16x32_bf16(ah, bl_, acc, 0, 0, 0);
    }
    const int rbase = bid * 16;
#pragma unroll
    for (int reg = 0; reg < 4; ++reg) {
      int row = rbase + kg * 4 + reg;
      out[(size_t)row * EE + nt * 16 + m] = fmaxf(acc[reg], 0.f);
    }
  }
#undef LOAD_X
#undef PROC_TILE
#undef P1_SOFTMAX
}

extern "C" void kernel_launch(void* const* d_in, const int* in_sizes, int n_in,
                              void* d_out, int out_size, void* d_ws, size_t ws_size,
                              hipStream_t stream) {
  (void)in_sizes; (void)n_in; (void)out_size; (void)ws_size;
  const float* self_vecs  = (const float*)d_in[0];
  const float* neigh_vecs = (const float*)d_in[1];
  const float* W_heads    = (const float*)d_in[2];
  const float* a_self     = (const float*)d_in[3];
  const float* a_neigh    = (const float*)d_in[4];
  const float* W_out      = (const float*)d_in[5];
  float* out              = (float*)d_out;

  char* ws = (char*)d_ws;
  unsigned short* P1Whi = (unsigned short*)ws;                    // 4 KB
  unsigned short* P1Wlo = (unsigned short*)(ws + 4096);           // 4 KB
  unsigned short* WBhi  = (unsigned short*)(ws + 8192);           // 128 KB
  unsigned short* WBlo  = (unsigned short*)(ws + 8192 + 131072);
  unsigned short* WOhi  = (unsigned short*)(ws + 8192 + 262144);  // 64 KB
  unsigned short* WOlo  = (unsigned short*)(ws + 8192 + 262144 + 65536);

  prep_kernel<<<(2048 + 65536 + 32768) / 256, 256, 0, stream>>>(
      W_heads, a_self, a_neigh, W_out, P1Whi, P1Wlo, WBhi, WBlo, WOhi, WOlo);

  fused_kernel<<<BB / 4, 512, 0, stream>>>(
      self_vecs, neigh_vecs, P1Whi, P1Wlo, WBhi, WBlo, WOhi, WOlo, out);
}